// Round 6
// baseline (1163.063 us; speedup 1.0000x reference)
//
#include <hip/hip_runtime.h>
#include <cstdint>

#define D 128
#define BKT_SHIFT 8
#define EDGES_PER_BLOCK 4096

typedef __attribute__((ext_vector_type(8))) short short8;
typedef __attribute__((ext_vector_type(4))) float floatx4;

__device__ __forceinline__ float elu_f(float x) {
    return x > 0.0f ? x : __expf(x) - 1.0f;
}

__device__ __forceinline__ void split_bf16(float a, unsigned short& hi, unsigned short& lo) {
    unsigned u = __builtin_bit_cast(unsigned, a);
    unsigned hb = u & 0xffff0000u;
    float hf = __builtin_bit_cast(float, hb);
    float rl = a - hf;
    unsigned ul = __builtin_bit_cast(unsigned, rl);
    hi = (unsigned short)(u >> 16);
    lo = (unsigned short)(ul >> 16);
}

// ================= bucketed CSR build =================
__global__ __launch_bounds__(256) void bucket_count_kernel(
    const int* __restrict__ dst, int* __restrict__ bcnt, int E, int NB) {
    __shared__ int lcnt[512];
    int t = threadIdx.x;
    lcnt[t] = 0; lcnt[t + 256] = 0;
    __syncthreads();
    int base = blockIdx.x * EDGES_PER_BLOCK;
#pragma unroll
    for (int i = 0; i < 16; ++i) {
        int idx = base + i * 256 + t;
        if (idx < E) atomicAdd(&lcnt[dst[idx] >> BKT_SHIFT], 1);
    }
    __syncthreads();
    for (int b = t; b < NB; b += 256) {
        int c = lcnt[b];
        if (c) atomicAdd(&bcnt[b], c);
    }
}

__global__ __launch_bounds__(512) void scan_buckets_kernel(
    const int* __restrict__ bcnt, int* __restrict__ bucketoff,
    int* __restrict__ gcursor, int NB, int E, int* __restrict__ rowptr, int N) {
    __shared__ int s[512];
    int t = threadIdx.x;
    s[t] = (t < NB) ? bcnt[t] : 0;
    __syncthreads();
    for (int off = 1; off < 512; off <<= 1) {
        int v = (t >= off) ? s[t - off] : 0;
        __syncthreads();
        s[t] += v;
        __syncthreads();
    }
    int excl = (t == 0) ? 0 : s[t - 1];
    if (t < NB) { bucketoff[t] = excl; gcursor[t] = excl; }
    if (t == 0) { bucketoff[NB] = E; rowptr[N] = E; }
}

__global__ __launch_bounds__(256) void bucket_scatter_kernel(
    const int* __restrict__ src, const int* __restrict__ dst,
    int* __restrict__ gcursor, int2* __restrict__ staging, int E, int NB) {
    __shared__ int lcnt[512];
    __shared__ int lbase[512];
    int t = threadIdx.x;
    lcnt[t] = 0; lcnt[t + 256] = 0;
    __syncthreads();
    int base = blockIdx.x * EDGES_PER_BLOCK;
    int s_[16], d_[16], r_[16];
#pragma unroll
    for (int i = 0; i < 16; ++i) {
        int idx = base + i * 256 + t;
        if (idx < E) {
            s_[i] = src[idx];
            d_[i] = dst[idx];
            r_[i] = atomicAdd(&lcnt[d_[i] >> BKT_SHIFT], 1);
        }
    }
    __syncthreads();
    for (int b = t; b < NB; b += 256) {
        int c = lcnt[b];
        if (c) lbase[b] = atomicAdd(&gcursor[b], c);
    }
    __syncthreads();
#pragma unroll
    for (int i = 0; i < 16; ++i) {
        int idx = base + i * 256 + t;
        if (idx < E) {
            int bkt = d_[i] >> BKT_SHIFT;
            staging[lbase[bkt] + r_[i]] = make_int2(s_[i], d_[i]);
        }
    }
}

__global__ __launch_bounds__(256) void bucket_build_kernel(
    const int2* __restrict__ staging, const int* __restrict__ bucketoff,
    int* __restrict__ rowptr, int* __restrict__ col, int N) {
    __shared__ int hcnt[256];
    __shared__ int hoff[256];
    int t = threadIdx.x;
    int node0 = blockIdx.x << BKT_SHIFT;
    int off0 = bucketoff[blockIdx.x], off1 = bucketoff[blockIdx.x + 1];
    hcnt[t] = 0;
    __syncthreads();
    for (int i = off0 + t; i < off1; i += 256)
        atomicAdd(&hcnt[staging[i].y - node0], 1);
    __syncthreads();
    hoff[t] = hcnt[t];
    __syncthreads();
    for (int off = 1; off < 256; off <<= 1) {
        int u = (t >= off) ? hoff[t - off] : 0;
        __syncthreads();
        hoff[t] += u;
        __syncthreads();
    }
    int myoff = (t == 0) ? 0 : hoff[t - 1];
    __syncthreads();
    hoff[t] = myoff;
    hcnt[t] = 0;
    if (node0 + t < N) rowptr[node0 + t] = off0 + myoff;
    __syncthreads();
    for (int i = off0 + t; i < off1; i += 256) {
        int2 p = staging[i];
        int dl = p.y - node0;
        int pos = off0 + hoff[dl] + atomicAdd(&hcnt[dl], 1);
        col[pos] = p.x;
    }
}

// ---------------- GIN aggregation: direct col loads, unroll 8, split bf16 out ----------------
__global__ __launch_bounds__(256) void aggregate_kernel(
    const float* __restrict__ h, const int* __restrict__ rowptr,
    const int* __restrict__ col, unsigned short* __restrict__ outh,
    unsigned short* __restrict__ outl, int N) {
    int node = blockIdx.x * 8 + (threadIdx.x >> 5);
    int q = threadIdx.x & 31;
    if (node >= N) return;
    const float4* h4 = (const float4*)h;
    int e0 = rowptr[node], e1 = rowptr[node + 1];
    float4 acc = h4[(size_t)node * 32 + q];
    int e = e0;
    for (; e + 7 < e1; e += 8) {
        int j0 = col[e],     j1 = col[e + 1], j2 = col[e + 2], j3 = col[e + 3];
        int j4 = col[e + 4], j5 = col[e + 5], j6 = col[e + 6], j7 = col[e + 7];
        float4 v0 = h4[(size_t)j0 * 32 + q];
        float4 v1 = h4[(size_t)j1 * 32 + q];
        float4 v2 = h4[(size_t)j2 * 32 + q];
        float4 v3 = h4[(size_t)j3 * 32 + q];
        float4 v4 = h4[(size_t)j4 * 32 + q];
        float4 v5 = h4[(size_t)j5 * 32 + q];
        float4 v6 = h4[(size_t)j6 * 32 + q];
        float4 v7 = h4[(size_t)j7 * 32 + q];
        acc.x += ((v0.x + v1.x) + (v2.x + v3.x)) + ((v4.x + v5.x) + (v6.x + v7.x));
        acc.y += ((v0.y + v1.y) + (v2.y + v3.y)) + ((v4.y + v5.y) + (v6.y + v7.y));
        acc.z += ((v0.z + v1.z) + (v2.z + v3.z)) + ((v4.z + v5.z) + (v6.z + v7.z));
        acc.w += ((v0.w + v1.w) + (v2.w + v3.w)) + ((v4.w + v5.w) + (v6.w + v7.w));
    }
    for (; e + 1 < e1; e += 2) {
        int j0 = col[e], j1 = col[e + 1];
        float4 v0 = h4[(size_t)j0 * 32 + q];
        float4 v1 = h4[(size_t)j1 * 32 + q];
        acc.x += v0.x + v1.x;
        acc.y += v0.y + v1.y;
        acc.z += v0.z + v1.z;
        acc.w += v0.w + v1.w;
    }
    if (e < e1) {
        float4 v = h4[(size_t)col[e] * 32 + q];
        acc.x += v.x; acc.y += v.y; acc.z += v.z; acc.w += v.w;
    }
    ushort4 hh, ll;
    split_bf16(acc.x, hh.x, ll.x);
    split_bf16(acc.y, hh.y, ll.y);
    split_bf16(acc.z, hh.z, ll.z);
    split_bf16(acc.w, hh.w, ll.w);
    *(ushort4*)&outh[(size_t)node * D + q * 4] = hh;
    *(ushort4*)&outl[(size_t)node * D + q * 4] = ll;
}

// ---------------- W prep: fragment-permuted bf16 hi/lo layout ----------------
// Wp[mat][tile(ks*8+nt)][lane][j] = W[l][k*D+n], n=nt*16+(lane&15), k=ks*32+(lane>>4)*8+j
__global__ void wprep_kernel(const float* __restrict__ W1, const float* __restrict__ W2,
                             unsigned short* __restrict__ Wph, unsigned short* __restrict__ Wpl,
                             int total) {
    int idx = blockIdx.x * 256 + threadIdx.x;
    if (idx >= total) return;
    int mat = idx >> 14;
    int rem = idx & 16383;
    int tile = rem >> 9;
    int lane = (rem >> 3) & 63;
    int j = rem & 7;
    int ks = tile >> 3, nt = tile & 7;
    int n = nt * 16 + (lane & 15);
    int k = ks * 32 + (lane >> 4) * 8 + j;
    int l = mat >> 1;
    const float* W = (mat & 1) ? W2 : W1;
    float v = W[(size_t)l * D * D + k * D + n];
    unsigned short h, lo;
    split_bf16(v, h, lo);
    Wph[idx] = h;
    Wpl[idx] = lo;
}

// ---------------- MFMA GEMM (split-bf16, 3 terms), 128x128 tile ----------------
// PRESPLIT: A from Ah/Al (bf16 pairs). else: A = elu(Z*scale+shift) from fp32 Z (BN fused).
template <bool PRESPLIT, bool ELU_OUT, bool STATS>
__global__ __launch_bounds__(256, 2) void gemm_mfma(
    const unsigned short* __restrict__ Ah, const unsigned short* __restrict__ Al,
    const float* __restrict__ Z,
    const unsigned short* __restrict__ Wph, const unsigned short* __restrict__ Wpl,
    const float* __restrict__ bias,
    const float* __restrict__ colsum_in, const float* __restrict__ gamma,
    const float* __restrict__ beta,
    float* __restrict__ outp, float* __restrict__ colsum_out, int N) {
    __shared__ unsigned short sAh[128 * 136];
    __shared__ unsigned short sAl[128 * 136];
    __shared__ float bnsum[2 * D];
    __shared__ float s_sc[D];
    __shared__ float s_sh[D];
    const int tid = threadIdx.x;
    const int row0 = blockIdx.x * 128;

    if (STATS && tid < 2 * D) bnsum[tid] = 0.f;

    if (PRESPLIT) {
#pragma unroll
        for (int it = 0; it < 8; ++it) {
            int idx = tid + it * 256;
            int r = idx >> 4;           // 0..127
            int k8 = (idx & 15) * 8;
            int gr = row0 + r;
            uint4 va = make_uint4(0u, 0u, 0u, 0u), vb = make_uint4(0u, 0u, 0u, 0u);
            if (gr < N) {
                va = *(const uint4*)&Ah[(size_t)gr * D + k8];
                vb = *(const uint4*)&Al[(size_t)gr * D + k8];
            }
            *(uint4*)&sAh[r * 136 + k8] = va;
            *(uint4*)&sAl[r * 136 + k8] = vb;
        }
    } else {
        if (tid < D) {
            float invN = 1.0f / (float)N;
            float mu = colsum_in[tid] * invN;
            float var = colsum_in[D + tid] * invN - mu * mu;
            float rs = rsqrtf(var + 1e-5f);
            float sc = gamma[tid] * rs;
            s_sc[tid] = sc;
            s_sh[tid] = beta[tid] - mu * sc;
        }
        __syncthreads();
#pragma unroll
        for (int it = 0; it < 16; ++it) {
            int idx = tid + it * 256;
            int r = idx >> 5;           // 0..127
            int c4 = idx & 31;
            int gr = row0 + r;
            float4 v = make_float4(0.f, 0.f, 0.f, 0.f);
            if (gr < N) v = *(const float4*)&Z[(size_t)gr * D + c4 * 4];
            float4 sc = *(const float4*)&s_sc[c4 * 4];
            float4 sh = *(const float4*)&s_sh[c4 * 4];
            v.x = elu_f(v.x * sc.x + sh.x);
            v.y = elu_f(v.y * sc.y + sh.y);
            v.z = elu_f(v.z * sc.z + sh.z);
            v.w = elu_f(v.w * sc.w + sh.w);
            ushort4 hh, ll;
            split_bf16(v.x, hh.x, ll.x);
            split_bf16(v.y, hh.y, ll.y);
            split_bf16(v.z, hh.z, ll.z);
            split_bf16(v.w, hh.w, ll.w);
            *(ushort4*)&sAh[r * 136 + c4 * 4] = hh;
            *(ushort4*)&sAl[r * 136 + c4 * 4] = ll;
        }
    }
    __syncthreads();

    const int wave = tid >> 6, lane = tid & 63;
    const int l15 = lane & 15, quad = lane >> 4;
    const short8* bph = (const short8*)Wph;
    const short8* bpl = (const short8*)Wpl;

    floatx4 acc[2][8];
#pragma unroll
    for (int mt = 0; mt < 2; ++mt)
#pragma unroll
        for (int nt = 0; nt < 8; ++nt)
            acc[mt][nt] = (floatx4){0.f, 0.f, 0.f, 0.f};

#pragma unroll
    for (int ks = 0; ks < 4; ++ks) {
        const int kf = ks * 32 + quad * 8;
        short8 ah[2], al[2];
#pragma unroll
        for (int mt = 0; mt < 2; ++mt) {
            int off = (wave * 32 + mt * 16 + l15) * 136 + kf;
            ah[mt] = *(const short8*)&sAh[off];
            al[mt] = *(const short8*)&sAl[off];
        }
#pragma unroll
        for (int nt = 0; nt < 8; ++nt) {
            int tIdx = (ks * 8 + nt) * 64 + lane;
            short8 bh = bph[tIdx];
            short8 bl = bpl[tIdx];
#pragma unroll
            for (int mt = 0; mt < 2; ++mt) {
                acc[mt][nt] = __builtin_amdgcn_mfma_f32_16x16x32_bf16(ah[mt], bh, acc[mt][nt], 0, 0, 0);
                acc[mt][nt] = __builtin_amdgcn_mfma_f32_16x16x32_bf16(ah[mt], bl, acc[mt][nt], 0, 0, 0);
                acc[mt][nt] = __builtin_amdgcn_mfma_f32_16x16x32_bf16(al[mt], bh, acc[mt][nt], 0, 0, 0);
            }
        }
    }

#pragma unroll
    for (int nt = 0; nt < 8; ++nt) {
        int c = nt * 16 + l15;
        float b = bias[c];
        float s = 0.f, s2 = 0.f;
#pragma unroll
        for (int mt = 0; mt < 2; ++mt) {
#pragma unroll
            for (int r = 0; r < 4; ++r) {
                int gm = row0 + wave * 32 + mt * 16 + quad * 4 + r;
                float v = acc[mt][nt][r] + b;
                if (ELU_OUT) v = elu_f(v);
                if (gm < N) {
                    outp[(size_t)gm * D + c] = v;
                    if (STATS) { s += v; s2 += v * v; }
                }
            }
        }
        if (STATS) {
            atomicAdd(&bnsum[c], s);
            atomicAdd(&bnsum[D + c], s2);
        }
    }
    if (STATS) {
        __syncthreads();
        if (tid < D) {
            atomicAdd(&colsum_out[tid], bnsum[tid]);
            atomicAdd(&colsum_out[D + tid], bnsum[D + tid]);
        }
    }
}

// ---------------- global mean pool ----------------
__global__ __launch_bounds__(128) void pool_kernel(
    const float* __restrict__ h, const int* __restrict__ batch,
    float* __restrict__ pooled, float* __restrict__ cnt, int N) {
    int c = threadIdx.x;
    int r0 = blockIdx.x * 256;
    if (r0 >= N) return;
    int rend = r0 + 256; if (rend > N) rend = N;
    int cur = batch[r0];
    float acc = 0.f;
    float cacc = 0.f;
    for (int r = r0; r < rend; ++r) {
        int b = batch[r];
        if (b != cur) {
            atomicAdd(&pooled[(size_t)cur * D + c], acc);
            if (c == 0) atomicAdd(&cnt[cur], cacc);
            acc = 0.f; cacc = 0.f; cur = b;
        }
        acc += h[(size_t)r * D + c];
        cacc += 1.f;
    }
    atomicAdd(&pooled[(size_t)cur * D + c], acc);
    if (c == 0) atomicAdd(&cnt[cur], cacc);
}

__global__ void final_linear_kernel(const float* __restrict__ pooled,
                                    const float* __restrict__ cnt,
                                    const float* __restrict__ linW,
                                    const float* __restrict__ linb,
                                    float* __restrict__ out, int G) {
    int t = blockIdx.x * blockDim.x + threadIdx.x;
    if (t >= G * 2) return;
    int g = t >> 1, o = t & 1;
    float inv = 1.0f / fmaxf(cnt[g], 1.0f);
    float s = linb[o];
    for (int c = 0; c < D; ++c)
        s += pooled[(size_t)g * D + c] * inv * linW[c * 2 + o];
    out[t] = s;
}

extern "C" void kernel_launch(void* const* d_in, const int* in_sizes, int n_in,
                              void* d_out, int out_size, void* d_ws, size_t ws_size,
                              hipStream_t stream) {
    const float* x      = (const float*)d_in[0];
    const int*  eidx    = (const int*)d_in[1];
    const int*  batch   = (const int*)d_in[2];
    const float* W1     = (const float*)d_in[3];
    const float* b1     = (const float*)d_in[4];
    const float* gamma  = (const float*)d_in[5];
    const float* beta   = (const float*)d_in[6];
    const float* W2     = (const float*)d_in[7];
    const float* b2     = (const float*)d_in[8];
    const float* linW   = (const float*)d_in[9];
    const float* linb   = (const float*)d_in[10];
    float* out = (float*)d_out;

    const int N = in_sizes[0] / D;
    const int E = in_sizes[1] / 2;
    const int L = in_sizes[3] / (D * D);
    const int G = out_size / 2;
    const int* esrc = eidx;
    const int* edst = eidx + E;
    const int NB = (N + 255) >> 8;

    size_t off = 0;
    auto carve = [&](size_t bytes) -> void* {
        void* p = (char*)d_ws + off;
        off += (bytes + 255) & ~(size_t)255;
        return p;
    };
    const size_t ND = (size_t)N * D;
    const int WTOT = 2 * L * D * D;
    unsigned short* aggh = (unsigned short*)carve(ND * 2);
    unsigned short* aggl = (unsigned short*)carve(ND * 2);
    float* z1     = (float*)carve(ND * 4);           // also aliased as CSR staging
    float* hbuf   = (float*)carve(ND * 4);
    unsigned short* Wph = (unsigned short*)carve((size_t)WTOT * 2);
    unsigned short* Wpl = (unsigned short*)carve((size_t)WTOT * 2);
    int* rowptr   = (int*)carve((size_t)(N + 1) * 4);
    int* col      = (int*)carve((size_t)E * 4);
    int* bcnt     = (int*)carve(512 * 4);            // contiguous with colsum4: one memset
    float* colsum4 = (float*)carve((size_t)4 * 2 * D * 4);
    int* bucketoff = (int*)carve(513 * 4);
    int* gcursor  = (int*)carve(512 * 4);
    float* pooled = (float*)carve((size_t)G * D * 4); // contiguous with cnt: one memset
    float* cnt    = (float*)carve((size_t)G * 4);
    int2* staging = (int2*)z1;
    (void)ws_size; (void)n_in;

    hipMemsetAsync(bcnt, 0, 512 * 4 + (size_t)4 * 2 * D * 4, stream);
    hipMemsetAsync(pooled, 0, (size_t)G * D * 4 + (size_t)G * 4, stream);

    const int EB = (E + EDGES_PER_BLOCK - 1) / EDGES_PER_BLOCK;
    bucket_count_kernel<<<EB, 256, 0, stream>>>(edst, bcnt, E, NB);
    scan_buckets_kernel<<<1, 512, 0, stream>>>(bcnt, bucketoff, gcursor, NB, E, rowptr, N);
    bucket_scatter_kernel<<<EB, 256, 0, stream>>>(esrc, edst, gcursor, staging, E, NB);
    bucket_build_kernel<<<NB, 256, 0, stream>>>(staging, bucketoff, rowptr, col, N);
    wprep_kernel<<<(WTOT + 255) / 256, 256, 0, stream>>>(W1, W2, Wph, Wpl, WTOT);

    const int gemm_grid = (N + 127) / 128;
    const int agg_grid = (N + 7) / 8;
    const float* hin = x;
    for (int l = 0; l < L; ++l) {
        float* colsum = colsum4 + (size_t)l * 2 * D;
        aggregate_kernel<<<agg_grid, 256, 0, stream>>>(hin, rowptr, col, aggh, aggl, N);
        gemm_mfma<true, false, true><<<gemm_grid, 256, 0, stream>>>(
            aggh, aggl, nullptr,
            Wph + (size_t)(l * 2) * D * D, Wpl + (size_t)(l * 2) * D * D,
            b1 + (size_t)l * D, nullptr, nullptr, nullptr, z1, colsum, N);
        gemm_mfma<false, true, false><<<gemm_grid, 256, 0, stream>>>(
            nullptr, nullptr, z1,
            Wph + (size_t)(l * 2 + 1) * D * D, Wpl + (size_t)(l * 2 + 1) * D * D,
            b2 + (size_t)l * D, colsum, gamma + (size_t)l * D, beta + (size_t)l * D,
            hbuf, nullptr, N);
        hin = hbuf;
    }

    pool_kernel<<<(N + 255) / 256, 128, 0, stream>>>(hbuf, batch, pooled, cnt, N);
    final_linear_kernel<<<(G * 2 + 255) / 256, 256, 0, stream>>>(pooled, cnt, linW, linb, out, G);
}

// Round 7
// 1073.764 us; speedup vs baseline: 1.0832x; 1.0832x over previous
//
#include <hip/hip_runtime.h>
#include <cstdint>

#define D 128
#define BKT_SHIFT 8
#define EDGES_PER_BLOCK 4096

typedef __attribute__((ext_vector_type(8))) short short8;
typedef __attribute__((ext_vector_type(4))) float floatx4;

__device__ __forceinline__ float elu_f(float x) {
    return x > 0.0f ? x : __expf(x) - 1.0f;
}

__device__ __forceinline__ void split_bf16(float a, unsigned short& hi, unsigned short& lo) {
    unsigned u = __builtin_bit_cast(unsigned, a);
    unsigned hb = u & 0xffff0000u;
    float hf = __builtin_bit_cast(float, hb);
    float rl = a - hf;
    unsigned ul = __builtin_bit_cast(unsigned, rl);
    hi = (unsigned short)(u >> 16);
    lo = (unsigned short)(ul >> 16);
}

// ================= bucketed CSR build =================
__global__ __launch_bounds__(256) void bucket_count_kernel(
    const int* __restrict__ dst, int* __restrict__ bcnt, int E, int NB) {
    __shared__ int lcnt[512];
    int t = threadIdx.x;
    lcnt[t] = 0; lcnt[t + 256] = 0;
    __syncthreads();
    int base = blockIdx.x * EDGES_PER_BLOCK;
#pragma unroll
    for (int i = 0; i < 16; ++i) {
        int idx = base + i * 256 + t;
        if (idx < E) atomicAdd(&lcnt[dst[idx] >> BKT_SHIFT], 1);
    }
    __syncthreads();
    for (int b = t; b < NB; b += 256) {
        int c = lcnt[b];
        if (c) atomicAdd(&bcnt[b], c);
    }
}

__global__ __launch_bounds__(512) void scan_buckets_kernel(
    const int* __restrict__ bcnt, int* __restrict__ bucketoff,
    int* __restrict__ gcursor, int NB, int E, int* __restrict__ rowptr, int N) {
    __shared__ int s[512];
    int t = threadIdx.x;
    s[t] = (t < NB) ? bcnt[t] : 0;
    __syncthreads();
    for (int off = 1; off < 512; off <<= 1) {
        int v = (t >= off) ? s[t - off] : 0;
        __syncthreads();
        s[t] += v;
        __syncthreads();
    }
    int excl = (t == 0) ? 0 : s[t - 1];
    if (t < NB) { bucketoff[t] = excl; gcursor[t] = excl; }
    if (t == 0) { bucketoff[NB] = E; rowptr[N] = E; }
}

__global__ __launch_bounds__(256) void bucket_scatter_kernel(
    const int* __restrict__ src, const int* __restrict__ dst,
    int* __restrict__ gcursor, int2* __restrict__ staging, int E, int NB) {
    __shared__ int lcnt[512];
    __shared__ int lbase[512];
    int t = threadIdx.x;
    lcnt[t] = 0; lcnt[t + 256] = 0;
    __syncthreads();
    int base = blockIdx.x * EDGES_PER_BLOCK;
    int s_[16], d_[16], r_[16];
#pragma unroll
    for (int i = 0; i < 16; ++i) {
        int idx = base + i * 256 + t;
        if (idx < E) {
            s_[i] = src[idx];
            d_[i] = dst[idx];
            r_[i] = atomicAdd(&lcnt[d_[i] >> BKT_SHIFT], 1);
        }
    }
    __syncthreads();
    for (int b = t; b < NB; b += 256) {
        int c = lcnt[b];
        if (c) lbase[b] = atomicAdd(&gcursor[b], c);
    }
    __syncthreads();
#pragma unroll
    for (int i = 0; i < 16; ++i) {
        int idx = base + i * 256 + t;
        if (idx < E) {
            int bkt = d_[i] >> BKT_SHIFT;
            staging[lbase[bkt] + r_[i]] = make_int2(s_[i], d_[i]);
        }
    }
}

__global__ __launch_bounds__(256) void bucket_build_kernel(
    const int2* __restrict__ staging, const int* __restrict__ bucketoff,
    int* __restrict__ rowptr, int* __restrict__ col, int N) {
    __shared__ int hcnt[256];
    __shared__ int hoff[256];
    int t = threadIdx.x;
    int node0 = blockIdx.x << BKT_SHIFT;
    int off0 = bucketoff[blockIdx.x], off1 = bucketoff[blockIdx.x + 1];
    hcnt[t] = 0;
    __syncthreads();
    for (int i = off0 + t; i < off1; i += 256)
        atomicAdd(&hcnt[staging[i].y - node0], 1);
    __syncthreads();
    hoff[t] = hcnt[t];
    __syncthreads();
    for (int off = 1; off < 256; off <<= 1) {
        int u = (t >= off) ? hoff[t - off] : 0;
        __syncthreads();
        hoff[t] += u;
        __syncthreads();
    }
    int myoff = (t == 0) ? 0 : hoff[t - 1];
    __syncthreads();
    hoff[t] = myoff;
    hcnt[t] = 0;
    if (node0 + t < N) rowptr[node0 + t] = off0 + myoff;
    __syncthreads();
    for (int i = off0 + t; i < off1; i += 256) {
        int2 p = staging[i];
        int dl = p.y - node0;
        int pos = off0 + hoff[dl] + atomicAdd(&hcnt[dl], 1);
        col[pos] = p.x;
    }
}

// ---------------- GIN aggregation: direct col loads, unroll 8, split bf16 out ----------------
__global__ __launch_bounds__(256) void aggregate_kernel(
    const float* __restrict__ h, const int* __restrict__ rowptr,
    const int* __restrict__ col, unsigned short* __restrict__ outh,
    unsigned short* __restrict__ outl, int N) {
    int node = blockIdx.x * 8 + (threadIdx.x >> 5);
    int q = threadIdx.x & 31;
    if (node >= N) return;
    const float4* h4 = (const float4*)h;
    int e0 = rowptr[node], e1 = rowptr[node + 1];
    float4 acc = h4[(size_t)node * 32 + q];
    int e = e0;
    for (; e + 7 < e1; e += 8) {
        int j0 = col[e],     j1 = col[e + 1], j2 = col[e + 2], j3 = col[e + 3];
        int j4 = col[e + 4], j5 = col[e + 5], j6 = col[e + 6], j7 = col[e + 7];
        float4 v0 = h4[(size_t)j0 * 32 + q];
        float4 v1 = h4[(size_t)j1 * 32 + q];
        float4 v2 = h4[(size_t)j2 * 32 + q];
        float4 v3 = h4[(size_t)j3 * 32 + q];
        float4 v4 = h4[(size_t)j4 * 32 + q];
        float4 v5 = h4[(size_t)j5 * 32 + q];
        float4 v6 = h4[(size_t)j6 * 32 + q];
        float4 v7 = h4[(size_t)j7 * 32 + q];
        acc.x += ((v0.x + v1.x) + (v2.x + v3.x)) + ((v4.x + v5.x) + (v6.x + v7.x));
        acc.y += ((v0.y + v1.y) + (v2.y + v3.y)) + ((v4.y + v5.y) + (v6.y + v7.y));
        acc.z += ((v0.z + v1.z) + (v2.z + v3.z)) + ((v4.z + v5.z) + (v6.z + v7.z));
        acc.w += ((v0.w + v1.w) + (v2.w + v3.w)) + ((v4.w + v5.w) + (v6.w + v7.w));
    }
    for (; e + 1 < e1; e += 2) {
        int j0 = col[e], j1 = col[e + 1];
        float4 v0 = h4[(size_t)j0 * 32 + q];
        float4 v1 = h4[(size_t)j1 * 32 + q];
        acc.x += v0.x + v1.x;
        acc.y += v0.y + v1.y;
        acc.z += v0.z + v1.z;
        acc.w += v0.w + v1.w;
    }
    if (e < e1) {
        float4 v = h4[(size_t)col[e] * 32 + q];
        acc.x += v.x; acc.y += v.y; acc.z += v.z; acc.w += v.w;
    }
    ushort4 hh, ll;
    split_bf16(acc.x, hh.x, ll.x);
    split_bf16(acc.y, hh.y, ll.y);
    split_bf16(acc.z, hh.z, ll.z);
    split_bf16(acc.w, hh.w, ll.w);
    *(ushort4*)&outh[(size_t)node * D + q * 4] = hh;
    *(ushort4*)&outl[(size_t)node * D + q * 4] = ll;
}

// ---------------- W prep: fragment-permuted bf16 hi/lo layout ----------------
// Wp[mat][tile(ks*8+nt)][lane][j] = W[l][k*D+n], n=nt*16+(lane&15), k=ks*32+(lane>>4)*8+j
__global__ void wprep_kernel(const float* __restrict__ W1, const float* __restrict__ W2,
                             unsigned short* __restrict__ Wph, unsigned short* __restrict__ Wpl,
                             int total) {
    int idx = blockIdx.x * 256 + threadIdx.x;
    if (idx >= total) return;
    int mat = idx >> 14;
    int rem = idx & 16383;
    int tile = rem >> 9;
    int lane = (rem >> 3) & 63;
    int j = rem & 7;
    int ks = tile >> 3, nt = tile & 7;
    int n = nt * 16 + (lane & 15);
    int k = ks * 32 + (lane >> 4) * 8 + j;
    int l = mat >> 1;
    const float* W = (mat & 1) ? W2 : W1;
    float v = W[(size_t)l * D * D + k * D + n];
    unsigned short h, lo;
    split_bf16(v, h, lo);
    Wph[idx] = h;
    Wpl[idx] = lo;
}

// ---------------- MFMA GEMM (split-bf16, 3 terms), 64x128 tile, 3 blocks/CU ----------------
// PRESPLIT: A from Ah/Al (bf16 pairs, pure copy staging).
// else: A = elu(Z*scale+shift) from fp32 Z (BN fused, scale/shift from colsum_in).
template <bool PRESPLIT, bool ELU_OUT, bool STATS>
__global__ __launch_bounds__(256, 3) void gemm_mfma(
    const unsigned short* __restrict__ Ah, const unsigned short* __restrict__ Al,
    const float* __restrict__ Z,
    const unsigned short* __restrict__ Wph, const unsigned short* __restrict__ Wpl,
    const float* __restrict__ bias,
    const float* __restrict__ colsum_in, const float* __restrict__ gamma,
    const float* __restrict__ beta,
    float* __restrict__ outp, float* __restrict__ colsum_out, int N) {
    __shared__ unsigned short sAh[64 * 136];
    __shared__ unsigned short sAl[64 * 136];
    __shared__ float bnsum[2 * D];
    __shared__ float s_sc[D];
    __shared__ float s_sh[D];
    const int tid = threadIdx.x;
    const int row0 = blockIdx.x * 64;

    if (STATS && tid < 2 * D) bnsum[tid] = 0.f;

    if (PRESPLIT) {
#pragma unroll
        for (int it = 0; it < 4; ++it) {
            int idx = tid + it * 256;
            int r = idx >> 4;           // 0..63
            int k8 = (idx & 15) * 8;
            int gr = row0 + r;
            uint4 va = make_uint4(0u, 0u, 0u, 0u), vb = make_uint4(0u, 0u, 0u, 0u);
            if (gr < N) {
                va = *(const uint4*)&Ah[(size_t)gr * D + k8];
                vb = *(const uint4*)&Al[(size_t)gr * D + k8];
            }
            *(uint4*)&sAh[r * 136 + k8] = va;
            *(uint4*)&sAl[r * 136 + k8] = vb;
        }
    } else {
        if (tid < D) {
            float invN = 1.0f / (float)N;
            float mu = colsum_in[tid] * invN;
            float var = colsum_in[D + tid] * invN - mu * mu;
            float rs = rsqrtf(var + 1e-5f);
            float sc = gamma[tid] * rs;
            s_sc[tid] = sc;
            s_sh[tid] = beta[tid] - mu * sc;
        }
        __syncthreads();
#pragma unroll
        for (int it = 0; it < 8; ++it) {
            int idx = tid + it * 256;
            int r = idx >> 5;           // 0..63
            int c4 = idx & 31;
            int gr = row0 + r;
            float4 v = make_float4(0.f, 0.f, 0.f, 0.f);
            if (gr < N) v = *(const float4*)&Z[(size_t)gr * D + c4 * 4];
            float4 sc = *(const float4*)&s_sc[c4 * 4];
            float4 sh = *(const float4*)&s_sh[c4 * 4];
            v.x = elu_f(v.x * sc.x + sh.x);
            v.y = elu_f(v.y * sc.y + sh.y);
            v.z = elu_f(v.z * sc.z + sh.z);
            v.w = elu_f(v.w * sc.w + sh.w);
            ushort4 hh, ll;
            split_bf16(v.x, hh.x, ll.x);
            split_bf16(v.y, hh.y, ll.y);
            split_bf16(v.z, hh.z, ll.z);
            split_bf16(v.w, hh.w, ll.w);
            *(ushort4*)&sAh[r * 136 + c4 * 4] = hh;
            *(ushort4*)&sAl[r * 136 + c4 * 4] = ll;
        }
    }
    __syncthreads();

    const int wave = tid >> 6, lane = tid & 63;
    const int wm = wave >> 1, wn = wave & 1;
    const int l15 = lane & 15, quad = lane >> 4;
    const short8* bph = (const short8*)Wph;
    const short8* bpl = (const short8*)Wpl;

    floatx4 acc[2][4];
#pragma unroll
    for (int mt = 0; mt < 2; ++mt)
#pragma unroll
        for (int nt = 0; nt < 4; ++nt)
            acc[mt][nt] = (floatx4){0.f, 0.f, 0.f, 0.f};

#pragma unroll
    for (int ks = 0; ks < 4; ++ks) {
        const int kf = ks * 32 + quad * 8;
        short8 bh[4], bl[4];
#pragma unroll
        for (int nt = 0; nt < 4; ++nt) {
            int tIdx = (ks * 8 + wn * 4 + nt) * 64 + lane;
            bh[nt] = bph[tIdx];
            bl[nt] = bpl[tIdx];
        }
        short8 ah[2], al[2];
#pragma unroll
        for (int mt = 0; mt < 2; ++mt) {
            int off = (wm * 32 + mt * 16 + l15) * 136 + kf;
            ah[mt] = *(const short8*)&sAh[off];
            al[mt] = *(const short8*)&sAl[off];
        }
#pragma unroll
        for (int mt = 0; mt < 2; ++mt)
#pragma unroll
            for (int nt = 0; nt < 4; ++nt) {
                acc[mt][nt] = __builtin_amdgcn_mfma_f32_16x16x32_bf16(ah[mt], bh[nt], acc[mt][nt], 0, 0, 0);
                acc[mt][nt] = __builtin_amdgcn_mfma_f32_16x16x32_bf16(ah[mt], bl[nt], acc[mt][nt], 0, 0, 0);
                acc[mt][nt] = __builtin_amdgcn_mfma_f32_16x16x32_bf16(al[mt], bh[nt], acc[mt][nt], 0, 0, 0);
            }
    }

#pragma unroll
    for (int nt = 0; nt < 4; ++nt) {
        int c = wn * 64 + nt * 16 + l15;
        float b = bias[c];
        float s = 0.f, s2 = 0.f;
#pragma unroll
        for (int mt = 0; mt < 2; ++mt) {
#pragma unroll
            for (int r = 0; r < 4; ++r) {
                int gm = row0 + wm * 32 + mt * 16 + quad * 4 + r;
                float v = acc[mt][nt][r] + b;
                if (ELU_OUT) v = elu_f(v);
                if (gm < N) {
                    outp[(size_t)gm * D + c] = v;
                    if (STATS) { s += v; s2 += v * v; }
                }
            }
        }
        if (STATS) {
            atomicAdd(&bnsum[c], s);
            atomicAdd(&bnsum[D + c], s2);
        }
    }
    if (STATS) {
        __syncthreads();
        if (tid < D) {
            atomicAdd(&colsum_out[tid], bnsum[tid]);
            atomicAdd(&colsum_out[D + tid], bnsum[D + tid]);
        }
    }
}

// ---------------- global mean pool ----------------
__global__ __launch_bounds__(128) void pool_kernel(
    const float* __restrict__ h, const int* __restrict__ batch,
    float* __restrict__ pooled, float* __restrict__ cnt, int N) {
    int c = threadIdx.x;
    int r0 = blockIdx.x * 256;
    if (r0 >= N) return;
    int rend = r0 + 256; if (rend > N) rend = N;
    int cur = batch[r0];
    float acc = 0.f;
    float cacc = 0.f;
    for (int r = r0; r < rend; ++r) {
        int b = batch[r];
        if (b != cur) {
            atomicAdd(&pooled[(size_t)cur * D + c], acc);
            if (c == 0) atomicAdd(&cnt[cur], cacc);
            acc = 0.f; cacc = 0.f; cur = b;
        }
        acc += h[(size_t)r * D + c];
        cacc += 1.f;
    }
    atomicAdd(&pooled[(size_t)cur * D + c], acc);
    if (c == 0) atomicAdd(&cnt[cur], cacc);
}

__global__ void final_linear_kernel(const float* __restrict__ pooled,
                                    const float* __restrict__ cnt,
                                    const float* __restrict__ linW,
                                    const float* __restrict__ linb,
                                    float* __restrict__ out, int G) {
    int t = blockIdx.x * blockDim.x + threadIdx.x;
    if (t >= G * 2) return;
    int g = t >> 1, o = t & 1;
    float inv = 1.0f / fmaxf(cnt[g], 1.0f);
    float s = linb[o];
    for (int c = 0; c < D; ++c)
        s += pooled[(size_t)g * D + c] * inv * linW[c * 2 + o];
    out[t] = s;
}

extern "C" void kernel_launch(void* const* d_in, const int* in_sizes, int n_in,
                              void* d_out, int out_size, void* d_ws, size_t ws_size,
                              hipStream_t stream) {
    const float* x      = (const float*)d_in[0];
    const int*  eidx    = (const int*)d_in[1];
    const int*  batch   = (const int*)d_in[2];
    const float* W1     = (const float*)d_in[3];
    const float* b1     = (const float*)d_in[4];
    const float* gamma  = (const float*)d_in[5];
    const float* beta   = (const float*)d_in[6];
    const float* W2     = (const float*)d_in[7];
    const float* b2     = (const float*)d_in[8];
    const float* linW   = (const float*)d_in[9];
    const float* linb   = (const float*)d_in[10];
    float* out = (float*)d_out;

    const int N = in_sizes[0] / D;
    const int E = in_sizes[1] / 2;
    const int L = in_sizes[3] / (D * D);
    const int G = out_size / 2;
    const int* esrc = eidx;
    const int* edst = eidx + E;
    const int NB = (N + 255) >> 8;

    size_t off = 0;
    auto carve = [&](size_t bytes) -> void* {
        void* p = (char*)d_ws + off;
        off += (bytes + 255) & ~(size_t)255;
        return p;
    };
    const size_t ND = (size_t)N * D;
    const int WTOT = 2 * L * D * D;
    unsigned short* aggh = (unsigned short*)carve(ND * 2);
    unsigned short* aggl = (unsigned short*)carve(ND * 2);
    float* z1     = (float*)carve(ND * 4);           // also aliased as CSR staging
    float* hbuf   = (float*)carve(ND * 4);
    unsigned short* Wph = (unsigned short*)carve((size_t)WTOT * 2);
    unsigned short* Wpl = (unsigned short*)carve((size_t)WTOT * 2);
    int* rowptr   = (int*)carve((size_t)(N + 1) * 4);
    int* col      = (int*)carve((size_t)E * 4);
    int* bcnt     = (int*)carve(512 * 4);            // contiguous with colsum4: one memset
    float* colsum4 = (float*)carve((size_t)4 * 2 * D * 4);
    int* bucketoff = (int*)carve(513 * 4);
    int* gcursor  = (int*)carve(512 * 4);
    float* pooled = (float*)carve((size_t)G * D * 4); // contiguous with cnt: one memset
    float* cnt    = (float*)carve((size_t)G * 4);
    int2* staging = (int2*)z1;
    (void)ws_size; (void)n_in;

    hipMemsetAsync(bcnt, 0, 512 * 4 + (size_t)4 * 2 * D * 4, stream);
    hipMemsetAsync(pooled, 0, (size_t)G * D * 4 + (size_t)G * 4, stream);

    const int EB = (E + EDGES_PER_BLOCK - 1) / EDGES_PER_BLOCK;
    bucket_count_kernel<<<EB, 256, 0, stream>>>(edst, bcnt, E, NB);
    scan_buckets_kernel<<<1, 512, 0, stream>>>(bcnt, bucketoff, gcursor, NB, E, rowptr, N);
    bucket_scatter_kernel<<<EB, 256, 0, stream>>>(esrc, edst, gcursor, staging, E, NB);
    bucket_build_kernel<<<NB, 256, 0, stream>>>(staging, bucketoff, rowptr, col, N);
    wprep_kernel<<<(WTOT + 255) / 256, 256, 0, stream>>>(W1, W2, Wph, Wpl, WTOT);

    const int gemm_grid = (N + 63) / 64;
    const int agg_grid = (N + 7) / 8;
    const float* hin = x;
    for (int l = 0; l < L; ++l) {
        float* colsum = colsum4 + (size_t)l * 2 * D;
        aggregate_kernel<<<agg_grid, 256, 0, stream>>>(hin, rowptr, col, aggh, aggl, N);
        gemm_mfma<true, false, true><<<gemm_grid, 256, 0, stream>>>(
            aggh, aggl, nullptr,
            Wph + (size_t)(l * 2) * D * D, Wpl + (size_t)(l * 2) * D * D,
            b1 + (size_t)l * D, nullptr, nullptr, nullptr, z1, colsum, N);
        gemm_mfma<false, true, false><<<gemm_grid, 256, 0, stream>>>(
            nullptr, nullptr, z1,
            Wph + (size_t)(l * 2 + 1) * D * D, Wpl + (size_t)(l * 2 + 1) * D * D,
            b2 + (size_t)l * D, colsum, gamma + (size_t)l * D, beta + (size_t)l * D,
            hbuf, nullptr, N);
        hin = hbuf;
    }

    pool_kernel<<<(N + 255) / 256, 128, 0, stream>>>(hbuf, batch, pooled, cnt, N);
    final_linear_kernel<<<(G * 2 + 255) / 256, 256, 0, stream>>>(pooled, cnt, linW, linb, out, G);
}

// Round 8
// 1061.027 us; speedup vs baseline: 1.0962x; 1.0120x over previous
//
#include <hip/hip_runtime.h>
#include <cstdint>

#define D 128
#define BKT_SHIFT 8
#define BKT_CAP 5120
#define EDGES_PER_BLOCK 4096

typedef __attribute__((ext_vector_type(8))) short short8;
typedef __attribute__((ext_vector_type(4))) float floatx4;

__device__ __forceinline__ float elu_f(float x) {
    return x > 0.0f ? x : __expf(x) - 1.0f;
}

__device__ __forceinline__ void split_bf16(float a, unsigned short& hi, unsigned short& lo) {
    unsigned u = __builtin_bit_cast(unsigned, a);
    unsigned hb = u & 0xffff0000u;
    float hf = __builtin_bit_cast(float, hb);
    float rl = a - hf;
    unsigned ul = __builtin_bit_cast(unsigned, rl);
    hi = (unsigned short)(u >> 16);
    lo = (unsigned short)(ul >> 16);
}

// ================= bucketed CSR build (bump-allocated, no prepass) =================
__global__ void init_cursor_kernel(int* __restrict__ gcursor, int NB) {
    int t = blockIdx.x * 256 + threadIdx.x;
    if (t < NB) gcursor[t] = t * BKT_CAP;
}

// multisplit (src,dst) pairs into padded bucket regions
__global__ __launch_bounds__(256) void bucket_scatter_kernel(
    const int* __restrict__ src, const int* __restrict__ dst,
    int* __restrict__ gcursor, int2* __restrict__ staging, int E, int NB) {
    __shared__ int lcnt[512];
    __shared__ int lbase[512];
    int t = threadIdx.x;
    lcnt[t] = 0; lcnt[t + 256] = 0;
    __syncthreads();
    int base = blockIdx.x * EDGES_PER_BLOCK;
    int s_[16], d_[16], r_[16];
#pragma unroll
    for (int i = 0; i < 16; ++i) {
        int idx = base + i * 256 + t;
        if (idx < E) {
            s_[i] = src[idx];
            d_[i] = dst[idx];
            r_[i] = atomicAdd(&lcnt[d_[i] >> BKT_SHIFT], 1);
        }
    }
    __syncthreads();
    for (int b = t; b < NB; b += 256) {
        int c = lcnt[b];
        if (c) lbase[b] = atomicAdd(&gcursor[b], c);
    }
    __syncthreads();
#pragma unroll
    for (int i = 0; i < 16; ++i) {
        int idx = base + i * 256 + t;
        if (idx < E) {
            int bkt = d_[i] >> BKT_SHIFT;
            staging[lbase[bkt] + r_[i]] = make_int2(s_[i], d_[i]);
        }
    }
}

// one block per bucket: local histogram+scan -> rowstart/rowend + col slice
__global__ __launch_bounds__(256) void bucket_build_kernel(
    const int2* __restrict__ staging, const int* __restrict__ gcursor,
    int* __restrict__ rowstart, int* __restrict__ rowend,
    int* __restrict__ col, int N) {
    __shared__ int hcnt[256];
    __shared__ int hoff[256];
    int t = threadIdx.x;
    int node0 = blockIdx.x << BKT_SHIFT;
    int off0 = blockIdx.x * BKT_CAP;
    int off1 = gcursor[blockIdx.x];     // off0 + bucket count after scatter
    hcnt[t] = 0;
    __syncthreads();
    for (int i = off0 + t; i < off1; i += 256)
        atomicAdd(&hcnt[staging[i].y - node0], 1);
    __syncthreads();
    int deg = hcnt[t];
    hoff[t] = deg;
    __syncthreads();
    for (int off = 1; off < 256; off <<= 1) {
        int u = (t >= off) ? hoff[t - off] : 0;
        __syncthreads();
        hoff[t] += u;
        __syncthreads();
    }
    int myoff = (t == 0) ? 0 : hoff[t - 1];
    __syncthreads();
    hoff[t] = myoff;
    hcnt[t] = 0;
    if (node0 + t < N) {
        rowstart[node0 + t] = off0 + myoff;
        rowend[node0 + t] = off0 + myoff + deg;
    }
    __syncthreads();
    for (int i = off0 + t; i < off1; i += 256) {
        int2 p = staging[i];
        int dl = p.y - node0;
        int pos = off0 + hoff[dl] + atomicAdd(&hcnt[dl], 1);
        col[pos] = p.x;
    }
}

// ---------------- GIN aggregation: direct col loads, unroll 8, split bf16 out ----------------
__global__ __launch_bounds__(256) void aggregate_kernel(
    const float* __restrict__ h, const int* __restrict__ rowstart,
    const int* __restrict__ rowend, const int* __restrict__ col,
    unsigned short* __restrict__ outh, unsigned short* __restrict__ outl, int N) {
    int node = blockIdx.x * 8 + (threadIdx.x >> 5);
    int q = threadIdx.x & 31;
    if (node >= N) return;
    const float4* h4 = (const float4*)h;
    int e0 = rowstart[node], e1 = rowend[node];
    float4 acc = h4[(size_t)node * 32 + q];
    int e = e0;
    for (; e + 7 < e1; e += 8) {
        int j0 = col[e],     j1 = col[e + 1], j2 = col[e + 2], j3 = col[e + 3];
        int j4 = col[e + 4], j5 = col[e + 5], j6 = col[e + 6], j7 = col[e + 7];
        float4 v0 = h4[(size_t)j0 * 32 + q];
        float4 v1 = h4[(size_t)j1 * 32 + q];
        float4 v2 = h4[(size_t)j2 * 32 + q];
        float4 v3 = h4[(size_t)j3 * 32 + q];
        float4 v4 = h4[(size_t)j4 * 32 + q];
        float4 v5 = h4[(size_t)j5 * 32 + q];
        float4 v6 = h4[(size_t)j6 * 32 + q];
        float4 v7 = h4[(size_t)j7 * 32 + q];
        acc.x += ((v0.x + v1.x) + (v2.x + v3.x)) + ((v4.x + v5.x) + (v6.x + v7.x));
        acc.y += ((v0.y + v1.y) + (v2.y + v3.y)) + ((v4.y + v5.y) + (v6.y + v7.y));
        acc.z += ((v0.z + v1.z) + (v2.z + v3.z)) + ((v4.z + v5.z) + (v6.z + v7.z));
        acc.w += ((v0.w + v1.w) + (v2.w + v3.w)) + ((v4.w + v5.w) + (v6.w + v7.w));
    }
    for (; e + 1 < e1; e += 2) {
        int j0 = col[e], j1 = col[e + 1];
        float4 v0 = h4[(size_t)j0 * 32 + q];
        float4 v1 = h4[(size_t)j1 * 32 + q];
        acc.x += v0.x + v1.x;
        acc.y += v0.y + v1.y;
        acc.z += v0.z + v1.z;
        acc.w += v0.w + v1.w;
    }
    if (e < e1) {
        float4 v = h4[(size_t)col[e] * 32 + q];
        acc.x += v.x; acc.y += v.y; acc.z += v.z; acc.w += v.w;
    }
    ushort4 hh, ll;
    split_bf16(acc.x, hh.x, ll.x);
    split_bf16(acc.y, hh.y, ll.y);
    split_bf16(acc.z, hh.z, ll.z);
    split_bf16(acc.w, hh.w, ll.w);
    *(ushort4*)&outh[(size_t)node * D + q * 4] = hh;
    *(ushort4*)&outl[(size_t)node * D + q * 4] = ll;
}

// ---------------- W prep: fragment-permuted bf16 hi/lo layout ----------------
__global__ void wprep_kernel(const float* __restrict__ W1, const float* __restrict__ W2,
                             unsigned short* __restrict__ Wph, unsigned short* __restrict__ Wpl,
                             int total) {
    int idx = blockIdx.x * 256 + threadIdx.x;
    if (idx >= total) return;
    int mat = idx >> 14;
    int rem = idx & 16383;
    int tile = rem >> 9;
    int lane = (rem >> 3) & 63;
    int j = rem & 7;
    int ks = tile >> 3, nt = tile & 7;
    int n = nt * 16 + (lane & 15);
    int k = ks * 32 + (lane >> 4) * 8 + j;
    int l = mat >> 1;
    const float* W = (mat & 1) ? W2 : W1;
    float v = W[(size_t)l * D * D + k * D + n];
    unsigned short h, lo;
    split_bf16(v, h, lo);
    Wph[idx] = h;
    Wpl[idx] = lo;
}

// ---------------- MFMA GEMM (split-bf16, 3 terms), 64x128 tile, 4 blocks/CU ----------------
template <bool PRESPLIT, bool ELU_OUT, bool STATS>
__global__ __launch_bounds__(256, 4) void gemm_mfma(
    const unsigned short* __restrict__ Ah, const unsigned short* __restrict__ Al,
    const float* __restrict__ Z,
    const unsigned short* __restrict__ Wph, const unsigned short* __restrict__ Wpl,
    const float* __restrict__ bias,
    const float* __restrict__ colsum_in, const float* __restrict__ gamma,
    const float* __restrict__ beta,
    float* __restrict__ outp, float* __restrict__ colsum_out, int N) {
    __shared__ unsigned short sAh[64 * 136];
    __shared__ unsigned short sAl[64 * 136];
    __shared__ float bnsum[2 * D];
    __shared__ float s_sc[D];
    __shared__ float s_sh[D];
    const int tid = threadIdx.x;
    const int row0 = blockIdx.x * 64;

    if (STATS && tid < 2 * D) bnsum[tid] = 0.f;

    if (PRESPLIT) {
#pragma unroll
        for (int it = 0; it < 4; ++it) {
            int idx = tid + it * 256;
            int r = idx >> 4;           // 0..63
            int k8 = (idx & 15) * 8;
            int gr = row0 + r;
            uint4 va = make_uint4(0u, 0u, 0u, 0u), vb = make_uint4(0u, 0u, 0u, 0u);
            if (gr < N) {
                va = *(const uint4*)&Ah[(size_t)gr * D + k8];
                vb = *(const uint4*)&Al[(size_t)gr * D + k8];
            }
            *(uint4*)&sAh[r * 136 + k8] = va;
            *(uint4*)&sAl[r * 136 + k8] = vb;
        }
    } else {
        if (tid < D) {
            float invN = 1.0f / (float)N;
            float mu = colsum_in[tid] * invN;
            float var = colsum_in[D + tid] * invN - mu * mu;
            float rs = rsqrtf(var + 1e-5f);
            float sc = gamma[tid] * rs;
            s_sc[tid] = sc;
            s_sh[tid] = beta[tid] - mu * sc;
        }
        __syncthreads();
#pragma unroll
        for (int it = 0; it < 8; ++it) {
            int idx = tid + it * 256;
            int r = idx >> 5;           // 0..63
            int c4 = idx & 31;
            int gr = row0 + r;
            float4 v = make_float4(0.f, 0.f, 0.f, 0.f);
            if (gr < N) v = *(const float4*)&Z[(size_t)gr * D + c4 * 4];
            float4 sc = *(const float4*)&s_sc[c4 * 4];
            float4 sh = *(const float4*)&s_sh[c4 * 4];
            v.x = elu_f(v.x * sc.x + sh.x);
            v.y = elu_f(v.y * sc.y + sh.y);
            v.z = elu_f(v.z * sc.z + sh.z);
            v.w = elu_f(v.w * sc.w + sh.w);
            ushort4 hh, ll;
            split_bf16(v.x, hh.x, ll.x);
            split_bf16(v.y, hh.y, ll.y);
            split_bf16(v.z, hh.z, ll.z);
            split_bf16(v.w, hh.w, ll.w);
            *(ushort4*)&sAh[r * 136 + c4 * 4] = hh;
            *(ushort4*)&sAl[r * 136 + c4 * 4] = ll;
        }
    }
    __syncthreads();

    const int wave = tid >> 6, lane = tid & 63;
    const int wm = wave >> 1, wn = wave & 1;
    const int l15 = lane & 15, quad = lane >> 4;
    const short8* bph = (const short8*)Wph;
    const short8* bpl = (const short8*)Wpl;

    floatx4 acc[2][4];
#pragma unroll
    for (int mt = 0; mt < 2; ++mt)
#pragma unroll
        for (int nt = 0; nt < 4; ++nt)
            acc[mt][nt] = (floatx4){0.f, 0.f, 0.f, 0.f};

#pragma unroll
    for (int ks = 0; ks < 4; ++ks) {
        const int kf = ks * 32 + quad * 8;
        short8 bh[4], bl[4];
#pragma unroll
        for (int nt = 0; nt < 4; ++nt) {
            int tIdx = (ks * 8 + wn * 4 + nt) * 64 + lane;
            bh[nt] = bph[tIdx];
            bl[nt] = bpl[tIdx];
        }
        short8 ah[2], al[2];
#pragma unroll
        for (int mt = 0; mt < 2; ++mt) {
            int off = (wm * 32 + mt * 16 + l15) * 136 + kf;
            ah[mt] = *(const short8*)&sAh[off];
            al[mt] = *(const short8*)&sAl[off];
        }
#pragma unroll
        for (int mt = 0; mt < 2; ++mt)
#pragma unroll
            for (int nt = 0; nt < 4; ++nt) {
                acc[mt][nt] = __builtin_amdgcn_mfma_f32_16x16x32_bf16(ah[mt], bh[nt], acc[mt][nt], 0, 0, 0);
                acc[mt][nt] = __builtin_amdgcn_mfma_f32_16x16x32_bf16(ah[mt], bl[nt], acc[mt][nt], 0, 0, 0);
                acc[mt][nt] = __builtin_amdgcn_mfma_f32_16x16x32_bf16(al[mt], bh[nt], acc[mt][nt], 0, 0, 0);
            }
    }

#pragma unroll
    for (int nt = 0; nt < 4; ++nt) {
        int c = wn * 64 + nt * 16 + l15;
        float b = bias[c];
        float s = 0.f, s2 = 0.f;
#pragma unroll
        for (int mt = 0; mt < 2; ++mt) {
#pragma unroll
            for (int r = 0; r < 4; ++r) {
                int gm = row0 + wm * 32 + mt * 16 + quad * 4 + r;
                float v = acc[mt][nt][r] + b;
                if (ELU_OUT) v = elu_f(v);
                if (gm < N) {
                    outp[(size_t)gm * D + c] = v;
                    if (STATS) { s += v; s2 += v * v; }
                }
            }
        }
        if (STATS) {
            atomicAdd(&bnsum[c], s);
            atomicAdd(&bnsum[D + c], s2);
        }
    }
    if (STATS) {
        __syncthreads();
        if (tid < D) {
            atomicAdd(&colsum_out[tid], bnsum[tid]);
            atomicAdd(&colsum_out[D + tid], bnsum[D + tid]);
        }
    }
}

// ---------------- global mean pool ----------------
__global__ __launch_bounds__(128) void pool_kernel(
    const float* __restrict__ h, const int* __restrict__ batch,
    float* __restrict__ pooled, float* __restrict__ cnt, int N) {
    int c = threadIdx.x;
    int r0 = blockIdx.x * 256;
    if (r0 >= N) return;
    int rend = r0 + 256; if (rend > N) rend = N;
    int cur = batch[r0];
    float acc = 0.f;
    float cacc = 0.f;
    for (int r = r0; r < rend; ++r) {
        int b = batch[r];
        if (b != cur) {
            atomicAdd(&pooled[(size_t)cur * D + c], acc);
            if (c == 0) atomicAdd(&cnt[cur], cacc);
            acc = 0.f; cacc = 0.f; cur = b;
        }
        acc += h[(size_t)r * D + c];
        cacc += 1.f;
    }
    atomicAdd(&pooled[(size_t)cur * D + c], acc);
    if (c == 0) atomicAdd(&cnt[cur], cacc);
}

__global__ void final_linear_kernel(const float* __restrict__ pooled,
                                    const float* __restrict__ cnt,
                                    const float* __restrict__ linW,
                                    const float* __restrict__ linb,
                                    float* __restrict__ out, int G) {
    int t = blockIdx.x * blockDim.x + threadIdx.x;
    if (t >= G * 2) return;
    int g = t >> 1, o = t & 1;
    float inv = 1.0f / fmaxf(cnt[g], 1.0f);
    float s = linb[o];
    for (int c = 0; c < D; ++c)
        s += pooled[(size_t)g * D + c] * inv * linW[c * 2 + o];
    out[t] = s;
}

extern "C" void kernel_launch(void* const* d_in, const int* in_sizes, int n_in,
                              void* d_out, int out_size, void* d_ws, size_t ws_size,
                              hipStream_t stream) {
    const float* x      = (const float*)d_in[0];
    const int*  eidx    = (const int*)d_in[1];
    const int*  batch   = (const int*)d_in[2];
    const float* W1     = (const float*)d_in[3];
    const float* b1     = (const float*)d_in[4];
    const float* gamma  = (const float*)d_in[5];
    const float* beta   = (const float*)d_in[6];
    const float* W2     = (const float*)d_in[7];
    const float* b2     = (const float*)d_in[8];
    const float* linW   = (const float*)d_in[9];
    const float* linb   = (const float*)d_in[10];
    float* out = (float*)d_out;

    const int N = in_sizes[0] / D;
    const int E = in_sizes[1] / 2;
    const int L = in_sizes[3] / (D * D);
    const int G = out_size / 2;
    const int* esrc = eidx;
    const int* edst = eidx + E;
    const int NB = (N + 255) >> 8;

    size_t off = 0;
    auto carve = [&](size_t bytes) -> void* {
        void* p = (char*)d_ws + off;
        off += (bytes + 255) & ~(size_t)255;
        return p;
    };
    const size_t ND = (size_t)N * D;
    const int WTOT = 2 * L * D * D;
    unsigned short* aggh = (unsigned short*)carve(ND * 2);
    unsigned short* aggl = (unsigned short*)carve(ND * 2);
    float* z1     = (float*)carve(ND * 4);           // also aliased as CSR staging (16MB < 51MB)
    float* hbuf   = (float*)carve(ND * 4);
    unsigned short* Wph = (unsigned short*)carve((size_t)WTOT * 2);
    unsigned short* Wpl = (unsigned short*)carve((size_t)WTOT * 2);
    int* rowstart = (int*)carve((size_t)N * 4);
    int* rowend   = (int*)carve((size_t)N * 4);
    int* col      = (int*)carve((size_t)NB * BKT_CAP * 4);
    float* colsum4 = (float*)carve((size_t)4 * 2 * D * 4);
    int* gcursor  = (int*)carve(512 * 4);
    float* pooled = (float*)carve((size_t)G * D * 4); // contiguous with cnt: one memset
    float* cnt    = (float*)carve((size_t)G * 4);
    int2* staging = (int2*)z1;
    (void)ws_size; (void)n_in;

    hipMemsetAsync(colsum4, 0, (size_t)4 * 2 * D * 4, stream);
    hipMemsetAsync(pooled, 0, (size_t)G * D * 4 + (size_t)G * 4, stream);

    const int EB = (E + EDGES_PER_BLOCK - 1) / EDGES_PER_BLOCK;
    init_cursor_kernel<<<(NB + 255) / 256, 256, 0, stream>>>(gcursor, NB);
    bucket_scatter_kernel<<<EB, 256, 0, stream>>>(esrc, edst, gcursor, staging, E, NB);
    bucket_build_kernel<<<NB, 256, 0, stream>>>(staging, gcursor, rowstart, rowend, col, N);
    wprep_kernel<<<(WTOT + 255) / 256, 256, 0, stream>>>(W1, W2, Wph, Wpl, WTOT);

    const int gemm_grid = (N + 63) / 64;
    const int agg_grid = (N + 7) / 8;
    const float* hin = x;
    for (int l = 0; l < L; ++l) {
        float* colsum = colsum4 + (size_t)l * 2 * D;
        aggregate_kernel<<<agg_grid, 256, 0, stream>>>(hin, rowstart, rowend, col, aggh, aggl, N);
        gemm_mfma<true, false, true><<<gemm_grid, 256, 0, stream>>>(
            aggh, aggl, nullptr,
            Wph + (size_t)(l * 2) * D * D, Wpl + (size_t)(l * 2) * D * D,
            b1 + (size_t)l * D, nullptr, nullptr, nullptr, z1, colsum, N);
        gemm_mfma<false, true, false><<<gemm_grid, 256, 0, stream>>>(
            nullptr, nullptr, z1,
            Wph + (size_t)(l * 2 + 1) * D * D, Wpl + (size_t)(l * 2 + 1) * D * D,
            b2 + (size_t)l * D, colsum, gamma + (size_t)l * D, beta + (size_t)l * D,
            hbuf, nullptr, N);
        hin = hbuf;
    }

    pool_kernel<<<(N + 255) / 256, 128, 0, stream>>>(hbuf, batch, pooled, cnt, N);
    final_linear_kernel<<<(G * 2 + 255) / 256, 256, 0, stream>>>(pooled, cnt, linW, linb, out, G);
}

// Round 9
// 924.873 us; speedup vs baseline: 1.2575x; 1.1472x over previous
//
#include <hip/hip_runtime.h>
#include <cstdint>

#define D 128
#define BKT_SHIFT 8
#define BKT_CAP 5120
#define EDGES_PER_BLOCK 4096
#define NREP 8

typedef __attribute__((ext_vector_type(8))) short short8;
typedef __attribute__((ext_vector_type(4))) float floatx4;

__device__ __forceinline__ float elu_f(float x) {
    return x > 0.0f ? x : __expf(x) - 1.0f;
}

__device__ __forceinline__ void split_bf16(float a, unsigned short& hi, unsigned short& lo) {
    unsigned u = __builtin_bit_cast(unsigned, a);
    unsigned hb = u & 0xffff0000u;
    float hf = __builtin_bit_cast(float, hb);
    float rl = a - hf;
    unsigned ul = __builtin_bit_cast(unsigned, rl);
    hi = (unsigned short)(u >> 16);
    lo = (unsigned short)(ul >> 16);
}

// ================= bucketed CSR build (bump-allocated, no prepass) =================
__global__ void init_cursor_kernel(int* __restrict__ gcursor, int NB) {
    int t = blockIdx.x * 256 + threadIdx.x;
    if (t < NB) gcursor[t] = t * BKT_CAP;
}

__global__ __launch_bounds__(256) void bucket_scatter_kernel(
    const int* __restrict__ src, const int* __restrict__ dst,
    int* __restrict__ gcursor, int2* __restrict__ staging, int E, int NB) {
    __shared__ int lcnt[512];
    __shared__ int lbase[512];
    int t = threadIdx.x;
    lcnt[t] = 0; lcnt[t + 256] = 0;
    __syncthreads();
    int base = blockIdx.x * EDGES_PER_BLOCK;
    int s_[16], d_[16], r_[16];
#pragma unroll
    for (int i = 0; i < 16; ++i) {
        int idx = base + i * 256 + t;
        if (idx < E) {
            s_[i] = src[idx];
            d_[i] = dst[idx];
            r_[i] = atomicAdd(&lcnt[d_[i] >> BKT_SHIFT], 1);
        }
    }
    __syncthreads();
    for (int b = t; b < NB; b += 256) {
        int c = lcnt[b];
        if (c) lbase[b] = atomicAdd(&gcursor[b], c);
    }
    __syncthreads();
#pragma unroll
    for (int i = 0; i < 16; ++i) {
        int idx = base + i * 256 + t;
        if (idx < E) {
            int bkt = d_[i] >> BKT_SHIFT;
            staging[lbase[bkt] + r_[i]] = make_int2(s_[i], d_[i]);
        }
    }
}

__global__ __launch_bounds__(256) void bucket_build_kernel(
    const int2* __restrict__ staging, const int* __restrict__ gcursor,
    int* __restrict__ rowstart, int* __restrict__ rowend,
    int* __restrict__ col, int N) {
    __shared__ int hcnt[256];
    __shared__ int hoff[256];
    int t = threadIdx.x;
    int node0 = blockIdx.x << BKT_SHIFT;
    int off0 = blockIdx.x * BKT_CAP;
    int off1 = gcursor[blockIdx.x];
    hcnt[t] = 0;
    __syncthreads();
    for (int i = off0 + t; i < off1; i += 256)
        atomicAdd(&hcnt[staging[i].y - node0], 1);
    __syncthreads();
    int deg = hcnt[t];
    hoff[t] = deg;
    __syncthreads();
    for (int off = 1; off < 256; off <<= 1) {
        int u = (t >= off) ? hoff[t - off] : 0;
        __syncthreads();
        hoff[t] += u;
        __syncthreads();
    }
    int myoff = (t == 0) ? 0 : hoff[t - 1];
    __syncthreads();
    hoff[t] = myoff;
    hcnt[t] = 0;
    if (node0 + t < N) {
        rowstart[node0 + t] = off0 + myoff;
        rowend[node0 + t] = off0 + myoff + deg;
    }
    __syncthreads();
    for (int i = off0 + t; i < off1; i += 256) {
        int2 p = staging[i];
        int dl = p.y - node0;
        int pos = off0 + hoff[dl] + atomicAdd(&hcnt[dl], 1);
        col[pos] = p.x;
    }
}

// ---------------- W prep: fragment-permuted bf16 hi/lo layout ----------------
__global__ void wprep_kernel(const float* __restrict__ W1, const float* __restrict__ W2,
                             unsigned short* __restrict__ Wph, unsigned short* __restrict__ Wpl,
                             int total) {
    int idx = blockIdx.x * 256 + threadIdx.x;
    if (idx >= total) return;
    int mat = idx >> 14;
    int rem = idx & 16383;
    int tile = rem >> 9;
    int lane = (rem >> 3) & 63;
    int j = rem & 7;
    int ks = tile >> 3, nt = tile & 7;
    int n = nt * 16 + (lane & 15);
    int k = ks * 32 + (lane >> 4) * 8 + j;
    int l = mat >> 1;
    const float* W = (mat & 1) ? W2 : W1;
    float v = W[(size_t)l * D * D + k * D + n];
    unsigned short h, lo;
    split_bf16(v, h, lo);
    Wph[idx] = h;
    Wpl[idx] = lo;
}

// ---------------- MFMA GEMM (split-bf16, 3 terms), 64x128 tile ----------------
// GATHER: A = h[node] + sum_neighbors h[j], gathered in staging (GIN agg fused).
// else:   A = elu(Z*scale+shift), scale/shift from 8-replica colsum_in (BN fused).
// STATS: col sum/sumsq of output -> colsum_out + (blockIdx&7)*2D (replicated).
template <bool GATHER, bool ELU_OUT, bool STATS>
__global__ __launch_bounds__(256, 4) void gemm_mfma(
    const float* __restrict__ Hin,
    const int* __restrict__ rowstart, const int* __restrict__ rowend,
    const int* __restrict__ col,
    const float* __restrict__ Z,
    const unsigned short* __restrict__ Wph, const unsigned short* __restrict__ Wpl,
    const float* __restrict__ bias,
    const float* __restrict__ colsum_in, const float* __restrict__ gamma,
    const float* __restrict__ beta,
    float* __restrict__ outp, float* __restrict__ colsum_out, int N) {
    __shared__ unsigned short sAh[64 * 136];
    __shared__ unsigned short sAl[64 * 136];
    __shared__ float bnsum[2 * D];
    __shared__ float s_sc[D];
    __shared__ float s_sh[D];
    const int tid = threadIdx.x;
    const int row0 = blockIdx.x * 64;

    if (STATS && tid < 2 * D) bnsum[tid] = 0.f;

    if (GATHER) {
        const int grp = tid >> 5;    // 0..7, each handles 8 rows
        const int q = tid & 31;      // float4 lane within row
        const float4* h4 = (const float4*)Hin;
        for (int i = 0; i < 8; ++i) {
            int r = grp * 8 + i;
            int node = row0 + r;
            float4 acc = make_float4(0.f, 0.f, 0.f, 0.f);
            if (node < N) {
                acc = h4[(size_t)node * 32 + q];
                int e0 = rowstart[node], e1 = rowend[node];
                int e = e0;
                for (; e + 7 < e1; e += 8) {
                    int j0 = col[e],     j1 = col[e + 1], j2 = col[e + 2], j3 = col[e + 3];
                    int j4 = col[e + 4], j5 = col[e + 5], j6 = col[e + 6], j7 = col[e + 7];
                    float4 v0 = h4[(size_t)j0 * 32 + q];
                    float4 v1 = h4[(size_t)j1 * 32 + q];
                    float4 v2 = h4[(size_t)j2 * 32 + q];
                    float4 v3 = h4[(size_t)j3 * 32 + q];
                    float4 v4 = h4[(size_t)j4 * 32 + q];
                    float4 v5 = h4[(size_t)j5 * 32 + q];
                    float4 v6 = h4[(size_t)j6 * 32 + q];
                    float4 v7 = h4[(size_t)j7 * 32 + q];
                    acc.x += ((v0.x + v1.x) + (v2.x + v3.x)) + ((v4.x + v5.x) + (v6.x + v7.x));
                    acc.y += ((v0.y + v1.y) + (v2.y + v3.y)) + ((v4.y + v5.y) + (v6.y + v7.y));
                    acc.z += ((v0.z + v1.z) + (v2.z + v3.z)) + ((v4.z + v5.z) + (v6.z + v7.z));
                    acc.w += ((v0.w + v1.w) + (v2.w + v3.w)) + ((v4.w + v5.w) + (v6.w + v7.w));
                }
                for (; e + 1 < e1; e += 2) {
                    int j0 = col[e], j1 = col[e + 1];
                    float4 v0 = h4[(size_t)j0 * 32 + q];
                    float4 v1 = h4[(size_t)j1 * 32 + q];
                    acc.x += v0.x + v1.x;
                    acc.y += v0.y + v1.y;
                    acc.z += v0.z + v1.z;
                    acc.w += v0.w + v1.w;
                }
                if (e < e1) {
                    float4 v = h4[(size_t)col[e] * 32 + q];
                    acc.x += v.x; acc.y += v.y; acc.z += v.z; acc.w += v.w;
                }
            }
            ushort4 hh, ll;
            split_bf16(acc.x, hh.x, ll.x);
            split_bf16(acc.y, hh.y, ll.y);
            split_bf16(acc.z, hh.z, ll.z);
            split_bf16(acc.w, hh.w, ll.w);
            *(ushort4*)&sAh[r * 136 + q * 4] = hh;
            *(ushort4*)&sAl[r * 136 + q * 4] = ll;
        }
    } else {
        if (tid < D) {
            float s = 0.f, s2 = 0.f;
#pragma unroll
            for (int rp = 0; rp < NREP; ++rp) {
                s  += colsum_in[rp * 2 * D + tid];
                s2 += colsum_in[rp * 2 * D + D + tid];
            }
            float invN = 1.0f / (float)N;
            float mu = s * invN;
            float var = s2 * invN - mu * mu;
            float rs = rsqrtf(var + 1e-5f);
            float sc = gamma[tid] * rs;
            s_sc[tid] = sc;
            s_sh[tid] = beta[tid] - mu * sc;
        }
        __syncthreads();
#pragma unroll
        for (int it = 0; it < 8; ++it) {
            int idx = tid + it * 256;
            int r = idx >> 5;
            int c4 = idx & 31;
            int gr = row0 + r;
            float4 v = make_float4(0.f, 0.f, 0.f, 0.f);
            if (gr < N) v = *(const float4*)&Z[(size_t)gr * D + c4 * 4];
            float4 sc = *(const float4*)&s_sc[c4 * 4];
            float4 sh = *(const float4*)&s_sh[c4 * 4];
            v.x = elu_f(v.x * sc.x + sh.x);
            v.y = elu_f(v.y * sc.y + sh.y);
            v.z = elu_f(v.z * sc.z + sh.z);
            v.w = elu_f(v.w * sc.w + sh.w);
            ushort4 hh, ll;
            split_bf16(v.x, hh.x, ll.x);
            split_bf16(v.y, hh.y, ll.y);
            split_bf16(v.z, hh.z, ll.z);
            split_bf16(v.w, hh.w, ll.w);
            *(ushort4*)&sAh[r * 136 + c4 * 4] = hh;
            *(ushort4*)&sAl[r * 136 + c4 * 4] = ll;
        }
    }
    __syncthreads();

    const int wave = tid >> 6, lane = tid & 63;
    const int wm = wave >> 1, wn = wave & 1;
    const int l15 = lane & 15, quad = lane >> 4;
    const short8* bph = (const short8*)Wph;
    const short8* bpl = (const short8*)Wpl;

    floatx4 acc[2][4];
#pragma unroll
    for (int mt = 0; mt < 2; ++mt)
#pragma unroll
        for (int nt = 0; nt < 4; ++nt)
            acc[mt][nt] = (floatx4){0.f, 0.f, 0.f, 0.f};

#pragma unroll
    for (int ks = 0; ks < 4; ++ks) {
        const int kf = ks * 32 + quad * 8;
        short8 bh[4], bl[4];
#pragma unroll
        for (int nt = 0; nt < 4; ++nt) {
            int tIdx = (ks * 8 + wn * 4 + nt) * 64 + lane;
            bh[nt] = bph[tIdx];
            bl[nt] = bpl[tIdx];
        }
        short8 ah[2], al[2];
#pragma unroll
        for (int mt = 0; mt < 2; ++mt) {
            int off = (wm * 32 + mt * 16 + l15) * 136 + kf;
            ah[mt] = *(const short8*)&sAh[off];
            al[mt] = *(const short8*)&sAl[off];
        }
#pragma unroll
        for (int mt = 0; mt < 2; ++mt)
#pragma unroll
            for (int nt = 0; nt < 4; ++nt) {
                acc[mt][nt] = __builtin_amdgcn_mfma_f32_16x16x32_bf16(ah[mt], bh[nt], acc[mt][nt], 0, 0, 0);
                acc[mt][nt] = __builtin_amdgcn_mfma_f32_16x16x32_bf16(ah[mt], bl[nt], acc[mt][nt], 0, 0, 0);
                acc[mt][nt] = __builtin_amdgcn_mfma_f32_16x16x32_bf16(al[mt], bh[nt], acc[mt][nt], 0, 0, 0);
            }
    }

#pragma unroll
    for (int nt = 0; nt < 4; ++nt) {
        int c = wn * 64 + nt * 16 + l15;
        float b = bias[c];
        float s = 0.f, s2 = 0.f;
#pragma unroll
        for (int mt = 0; mt < 2; ++mt) {
#pragma unroll
            for (int r = 0; r < 4; ++r) {
                int gm = row0 + wm * 32 + mt * 16 + quad * 4 + r;
                float v = acc[mt][nt][r] + b;
                if (ELU_OUT) v = elu_f(v);
                if (gm < N) {
                    outp[(size_t)gm * D + c] = v;
                    if (STATS) { s += v; s2 += v * v; }
                }
            }
        }
        if (STATS) {
            atomicAdd(&bnsum[c], s);
            atomicAdd(&bnsum[D + c], s2);
        }
    }
    if (STATS) {
        __syncthreads();
        float* rep = colsum_out + (size_t)(blockIdx.x & (NREP - 1)) * 2 * D;
        if (tid < D) {
            atomicAdd(&rep[tid], bnsum[tid]);
            atomicAdd(&rep[D + tid], bnsum[D + tid]);
        }
    }
}

// ---------------- global mean pool ----------------
__global__ __launch_bounds__(128) void pool_kernel(
    const float* __restrict__ h, const int* __restrict__ batch,
    float* __restrict__ pooled, float* __restrict__ cnt, int N) {
    int c = threadIdx.x;
    int r0 = blockIdx.x * 256;
    if (r0 >= N) return;
    int rend = r0 + 256; if (rend > N) rend = N;
    int cur = batch[r0];
    float acc = 0.f;
    float cacc = 0.f;
    for (int r = r0; r < rend; ++r) {
        int b = batch[r];
        if (b != cur) {
            atomicAdd(&pooled[(size_t)cur * D + c], acc);
            if (c == 0) atomicAdd(&cnt[cur], cacc);
            acc = 0.f; cacc = 0.f; cur = b;
        }
        acc += h[(size_t)r * D + c];
        cacc += 1.f;
    }
    atomicAdd(&pooled[(size_t)cur * D + c], acc);
    if (c == 0) atomicAdd(&cnt[cur], cacc);
}

__global__ void final_linear_kernel(const float* __restrict__ pooled,
                                    const float* __restrict__ cnt,
                                    const float* __restrict__ linW,
                                    const float* __restrict__ linb,
                                    float* __restrict__ out, int G) {
    int t = blockIdx.x * blockDim.x + threadIdx.x;
    if (t >= G * 2) return;
    int g = t >> 1, o = t & 1;
    float inv = 1.0f / fmaxf(cnt[g], 1.0f);
    float s = linb[o];
    for (int c = 0; c < D; ++c)
        s += pooled[(size_t)g * D + c] * inv * linW[c * 2 + o];
    out[t] = s;
}

extern "C" void kernel_launch(void* const* d_in, const int* in_sizes, int n_in,
                              void* d_out, int out_size, void* d_ws, size_t ws_size,
                              hipStream_t stream) {
    const float* x      = (const float*)d_in[0];
    const int*  eidx    = (const int*)d_in[1];
    const int*  batch   = (const int*)d_in[2];
    const float* W1     = (const float*)d_in[3];
    const float* b1     = (const float*)d_in[4];
    const float* gamma  = (const float*)d_in[5];
    const float* beta   = (const float*)d_in[6];
    const float* W2     = (const float*)d_in[7];
    const float* b2     = (const float*)d_in[8];
    const float* linW   = (const float*)d_in[9];
    const float* linb   = (const float*)d_in[10];
    float* out = (float*)d_out;

    const int N = in_sizes[0] / D;
    const int E = in_sizes[1] / 2;
    const int L = in_sizes[3] / (D * D);
    const int G = out_size / 2;
    const int* esrc = eidx;
    const int* edst = eidx + E;
    const int NB = (N + 255) >> 8;

    size_t off = 0;
    auto carve = [&](size_t bytes) -> void* {
        void* p = (char*)d_ws + off;
        off += (bytes + 255) & ~(size_t)255;
        return p;
    };
    const size_t ND = (size_t)N * D;
    const int WTOT = 2 * L * D * D;
    float* z1     = (float*)carve(ND * 4);           // also aliased as CSR staging
    float* hbuf   = (float*)carve(ND * 4);
    unsigned short* Wph = (unsigned short*)carve((size_t)WTOT * 2);
    unsigned short* Wpl = (unsigned short*)carve((size_t)WTOT * 2);
    int* rowstart = (int*)carve((size_t)N * 4);
    int* rowend   = (int*)carve((size_t)N * 4);
    int* col      = (int*)carve((size_t)NB * BKT_CAP * 4);
    float* colsum4 = (float*)carve((size_t)4 * NREP * 2 * D * 4);
    int* gcursor  = (int*)carve(512 * 4);
    float* pooled = (float*)carve((size_t)G * D * 4); // contiguous with cnt: one memset
    float* cnt    = (float*)carve((size_t)G * 4);
    int2* staging = (int2*)z1;
    (void)ws_size; (void)n_in;

    hipMemsetAsync(colsum4, 0, (size_t)4 * NREP * 2 * D * 4, stream);
    hipMemsetAsync(pooled, 0, (size_t)G * D * 4 + (size_t)G * 4, stream);

    const int EB = (E + EDGES_PER_BLOCK - 1) / EDGES_PER_BLOCK;
    init_cursor_kernel<<<(NB + 255) / 256, 256, 0, stream>>>(gcursor, NB);
    bucket_scatter_kernel<<<EB, 256, 0, stream>>>(esrc, edst, gcursor, staging, E, NB);
    bucket_build_kernel<<<NB, 256, 0, stream>>>(staging, gcursor, rowstart, rowend, col, N);
    wprep_kernel<<<(WTOT + 255) / 256, 256, 0, stream>>>(W1, W2, Wph, Wpl, WTOT);

    const int gemm_grid = (N + 63) / 64;
    const float* hin = x;
    for (int l = 0; l < L; ++l) {
        float* colsum = colsum4 + (size_t)l * NREP * 2 * D;
        gemm_mfma<true, false, true><<<gemm_grid, 256, 0, stream>>>(
            hin, rowstart, rowend, col, nullptr,
            Wph + (size_t)(l * 2) * D * D, Wpl + (size_t)(l * 2) * D * D,
            b1 + (size_t)l * D, nullptr, nullptr, nullptr, z1, colsum, N);
        gemm_mfma<false, true, false><<<gemm_grid, 256, 0, stream>>>(
            nullptr, nullptr, nullptr, nullptr, z1,
            Wph + (size_t)(l * 2 + 1) * D * D, Wpl + (size_t)(l * 2 + 1) * D * D,
            b2 + (size_t)l * D, colsum, gamma + (size_t)l * D, beta + (size_t)l * D,
            hbuf, nullptr, N);
        hin = hbuf;
    }

    pool_kernel<<<(N + 255) / 256, 128, 0, stream>>>(hbuf, batch, pooled, cnt, N);
    final_linear_kernel<<<(G * 2 + 255) / 256, 256, 0, stream>>>(pooled, cnt, linW, linb, out, G);
}

// Round 10
// 862.817 us; speedup vs baseline: 1.3480x; 1.0719x over previous
//
#include <hip/hip_runtime.h>
#include <cstdint>

#define D 128
#define BKT_SHIFT 8
#define BKT_CAP 5120
#define EDGES_PER_BLOCK 4096
#define NREP 8

typedef __attribute__((ext_vector_type(8))) short short8;
typedef __attribute__((ext_vector_type(4))) float floatx4;
typedef __attribute__((ext_vector_type(4))) _Float16 half4;

__device__ __forceinline__ float elu_f(float x) {
    return x > 0.0f ? x : __expf(x) - 1.0f;
}

__device__ __forceinline__ void split_bf16(float a, unsigned short& hi, unsigned short& lo) {
    unsigned u = __builtin_bit_cast(unsigned, a);
    unsigned hb = u & 0xffff0000u;
    float hf = __builtin_bit_cast(float, hb);
    float rl = a - hf;
    unsigned ul = __builtin_bit_cast(unsigned, rl);
    hi = (unsigned short)(u >> 16);
    lo = (unsigned short)(ul >> 16);
}

// ================= bucketed CSR build (bump-allocated, no prepass) =================
__global__ void init_cursor_kernel(int* __restrict__ gcursor, int NB) {
    int t = blockIdx.x * 256 + threadIdx.x;
    if (t < NB) gcursor[t] = t * BKT_CAP;
}

__global__ __launch_bounds__(256) void bucket_scatter_kernel(
    const int* __restrict__ src, const int* __restrict__ dst,
    int* __restrict__ gcursor, int2* __restrict__ staging, int E, int NB) {
    __shared__ int lcnt[512];
    __shared__ int lbase[512];
    int t = threadIdx.x;
    lcnt[t] = 0; lcnt[t + 256] = 0;
    __syncthreads();
    int base = blockIdx.x * EDGES_PER_BLOCK;
    int s_[16], d_[16], r_[16];
#pragma unroll
    for (int i = 0; i < 16; ++i) {
        int idx = base + i * 256 + t;
        if (idx < E) {
            s_[i] = src[idx];
            d_[i] = dst[idx];
            r_[i] = atomicAdd(&lcnt[d_[i] >> BKT_SHIFT], 1);
        }
    }
    __syncthreads();
    for (int b = t; b < NB; b += 256) {
        int c = lcnt[b];
        if (c) lbase[b] = atomicAdd(&gcursor[b], c);
    }
    __syncthreads();
#pragma unroll
    for (int i = 0; i < 16; ++i) {
        int idx = base + i * 256 + t;
        if (idx < E) {
            int bkt = d_[i] >> BKT_SHIFT;
            staging[lbase[bkt] + r_[i]] = make_int2(s_[i], d_[i]);
        }
    }
}

__global__ __launch_bounds__(256) void bucket_build_kernel(
    const int2* __restrict__ staging, const int* __restrict__ gcursor,
    int* __restrict__ rowstart, int* __restrict__ rowend,
    int* __restrict__ col, int N) {
    __shared__ int hcnt[256];
    __shared__ int hoff[256];
    int t = threadIdx.x;
    int node0 = blockIdx.x << BKT_SHIFT;
    int off0 = blockIdx.x * BKT_CAP;
    int off1 = gcursor[blockIdx.x];
    hcnt[t] = 0;
    __syncthreads();
    for (int i = off0 + t; i < off1; i += 256)
        atomicAdd(&hcnt[staging[i].y - node0], 1);
    __syncthreads();
    int deg = hcnt[t];
    hoff[t] = deg;
    __syncthreads();
    for (int off = 1; off < 256; off <<= 1) {
        int u = (t >= off) ? hoff[t - off] : 0;
        __syncthreads();
        hoff[t] += u;
        __syncthreads();
    }
    int myoff = (t == 0) ? 0 : hoff[t - 1];
    __syncthreads();
    hoff[t] = myoff;
    hcnt[t] = 0;
    if (node0 + t < N) {
        rowstart[node0 + t] = off0 + myoff;
        rowend[node0 + t] = off0 + myoff + deg;
    }
    __syncthreads();
    for (int i = off0 + t; i < off1; i += 256) {
        int2 p = staging[i];
        int dl = p.y - node0;
        int pos = off0 + hoff[dl] + atomicAdd(&hcnt[dl], 1);
        col[pos] = p.x;
    }
}

// ---------------- fp32 -> fp16 convert (for x before layer 0) ----------------
__global__ void to_half_kernel(const float* __restrict__ in, _Float16* __restrict__ outp, int n4) {
    int i = blockIdx.x * 256 + threadIdx.x;
    if (i >= n4) return;
    float4 v = ((const float4*)in)[i];
    half4 h = {(_Float16)v.x, (_Float16)v.y, (_Float16)v.z, (_Float16)v.w};
    ((half4*)outp)[i] = h;
}

// ---------------- W prep: fragment-permuted bf16 hi/lo layout ----------------
__global__ void wprep_kernel(const float* __restrict__ W1, const float* __restrict__ W2,
                             unsigned short* __restrict__ Wph, unsigned short* __restrict__ Wpl,
                             int total) {
    int idx = blockIdx.x * 256 + threadIdx.x;
    if (idx >= total) return;
    int mat = idx >> 14;
    int rem = idx & 16383;
    int tile = rem >> 9;
    int lane = (rem >> 3) & 63;
    int j = rem & 7;
    int ks = tile >> 3, nt = tile & 7;
    int n = nt * 16 + (lane & 15);
    int k = ks * 32 + (lane >> 4) * 8 + j;
    int l = mat >> 1;
    const float* W = (mat & 1) ? W2 : W1;
    float v = W[(size_t)l * D * D + k * D + n];
    unsigned short h, lo;
    split_bf16(v, h, lo);
    Wph[idx] = h;
    Wpl[idx] = lo;
}

// ---------------- MFMA GEMM (split-bf16, 3 terms), 64x128 tile ----------------
// GATHER: A = h_fp32[node] + sum_neighbors h_fp16[j] (GIN agg fused in staging).
// else:   A = elu(Z*scale+shift), scale/shift from 8-replica colsum_in (BN fused).
// ELU_OUT also writes fp16 copy of output (next layer's gather source).
template <bool GATHER, bool ELU_OUT, bool STATS>
__global__ __launch_bounds__(256, 4) void gemm_mfma(
    const float* __restrict__ Hin, const _Float16* __restrict__ Hh,
    const int* __restrict__ rowstart, const int* __restrict__ rowend,
    const int* __restrict__ col,
    const float* __restrict__ Z,
    const unsigned short* __restrict__ Wph, const unsigned short* __restrict__ Wpl,
    const float* __restrict__ bias,
    const float* __restrict__ colsum_in, const float* __restrict__ gamma,
    const float* __restrict__ beta,
    float* __restrict__ outp, _Float16* __restrict__ outh16,
    float* __restrict__ colsum_out, int N) {
    __shared__ unsigned short sAh[64 * 136];
    __shared__ unsigned short sAl[64 * 136];
    __shared__ float bnsum[2 * D];
    __shared__ float s_sc[D];
    __shared__ float s_sh[D];
    const int tid = threadIdx.x;
    const int row0 = blockIdx.x * 64;

    if (STATS && tid < 2 * D) bnsum[tid] = 0.f;

    if (GATHER) {
        const int grp = tid >> 5;    // 0..7, each handles 8 rows
        const int q = tid & 31;      // half4/float4 lane within row
        const float4* h4 = (const float4*)Hin;
        const half4* hh4 = (const half4*)Hh;
        for (int i = 0; i < 8; ++i) {
            int r = grp * 8 + i;
            int node = row0 + r;
            float4 acc = make_float4(0.f, 0.f, 0.f, 0.f);
            if (node < N) {
                acc = h4[(size_t)node * 32 + q];
                int e0 = rowstart[node], e1 = rowend[node];
                int e = e0;
                for (; e + 7 < e1; e += 8) {
                    int j0 = col[e],     j1 = col[e + 1], j2 = col[e + 2], j3 = col[e + 3];
                    int j4 = col[e + 4], j5 = col[e + 5], j6 = col[e + 6], j7 = col[e + 7];
                    half4 v0 = hh4[(size_t)j0 * 32 + q];
                    half4 v1 = hh4[(size_t)j1 * 32 + q];
                    half4 v2 = hh4[(size_t)j2 * 32 + q];
                    half4 v3 = hh4[(size_t)j3 * 32 + q];
                    half4 v4 = hh4[(size_t)j4 * 32 + q];
                    half4 v5 = hh4[(size_t)j5 * 32 + q];
                    half4 v6 = hh4[(size_t)j6 * 32 + q];
                    half4 v7 = hh4[(size_t)j7 * 32 + q];
                    acc.x += ((float)v0[0] + (float)v1[0] + (float)v2[0] + (float)v3[0])
                           + ((float)v4[0] + (float)v5[0] + (float)v6[0] + (float)v7[0]);
                    acc.y += ((float)v0[1] + (float)v1[1] + (float)v2[1] + (float)v3[1])
                           + ((float)v4[1] + (float)v5[1] + (float)v6[1] + (float)v7[1]);
                    acc.z += ((float)v0[2] + (float)v1[2] + (float)v2[2] + (float)v3[2])
                           + ((float)v4[2] + (float)v5[2] + (float)v6[2] + (float)v7[2]);
                    acc.w += ((float)v0[3] + (float)v1[3] + (float)v2[3] + (float)v3[3])
                           + ((float)v4[3] + (float)v5[3] + (float)v6[3] + (float)v7[3]);
                }
                for (; e < e1; ++e) {
                    half4 v = hh4[(size_t)col[e] * 32 + q];
                    acc.x += (float)v[0]; acc.y += (float)v[1];
                    acc.z += (float)v[2]; acc.w += (float)v[3];
                }
            }
            ushort4 hh, ll;
            split_bf16(acc.x, hh.x, ll.x);
            split_bf16(acc.y, hh.y, ll.y);
            split_bf16(acc.z, hh.z, ll.z);
            split_bf16(acc.w, hh.w, ll.w);
            *(ushort4*)&sAh[r * 136 + q * 4] = hh;
            *(ushort4*)&sAl[r * 136 + q * 4] = ll;
        }
    } else {
        if (tid < D) {
            float s = 0.f, s2 = 0.f;
#pragma unroll
            for (int rp = 0; rp < NREP; ++rp) {
                s  += colsum_in[rp * 2 * D + tid];
                s2 += colsum_in[rp * 2 * D + D + tid];
            }
            float invN = 1.0f / (float)N;
            float mu = s * invN;
            float var = s2 * invN - mu * mu;
            float rs = rsqrtf(var + 1e-5f);
            float sc = gamma[tid] * rs;
            s_sc[tid] = sc;
            s_sh[tid] = beta[tid] - mu * sc;
        }
        __syncthreads();
#pragma unroll
        for (int it = 0; it < 8; ++it) {
            int idx = tid + it * 256;
            int r = idx >> 5;
            int c4 = idx & 31;
            int gr = row0 + r;
            float4 v = make_float4(0.f, 0.f, 0.f, 0.f);
            if (gr < N) v = *(const float4*)&Z[(size_t)gr * D + c4 * 4];
            float4 sc = *(const float4*)&s_sc[c4 * 4];
            float4 sh = *(const float4*)&s_sh[c4 * 4];
            v.x = elu_f(v.x * sc.x + sh.x);
            v.y = elu_f(v.y * sc.y + sh.y);
            v.z = elu_f(v.z * sc.z + sh.z);
            v.w = elu_f(v.w * sc.w + sh.w);
            ushort4 hh, ll;
            split_bf16(v.x, hh.x, ll.x);
            split_bf16(v.y, hh.y, ll.y);
            split_bf16(v.z, hh.z, ll.z);
            split_bf16(v.w, hh.w, ll.w);
            *(ushort4*)&sAh[r * 136 + c4 * 4] = hh;
            *(ushort4*)&sAl[r * 136 + c4 * 4] = ll;
        }
    }
    __syncthreads();

    const int wave = tid >> 6, lane = tid & 63;
    const int wm = wave >> 1, wn = wave & 1;
    const int l15 = lane & 15, quad = lane >> 4;
    const short8* bph = (const short8*)Wph;
    const short8* bpl = (const short8*)Wpl;

    floatx4 acc[2][4];
#pragma unroll
    for (int mt = 0; mt < 2; ++mt)
#pragma unroll
        for (int nt = 0; nt < 4; ++nt)
            acc[mt][nt] = (floatx4){0.f, 0.f, 0.f, 0.f};

#pragma unroll
    for (int ks = 0; ks < 4; ++ks) {
        const int kf = ks * 32 + quad * 8;
        short8 bh[4], bl[4];
#pragma unroll
        for (int nt = 0; nt < 4; ++nt) {
            int tIdx = (ks * 8 + wn * 4 + nt) * 64 + lane;
            bh[nt] = bph[tIdx];
            bl[nt] = bpl[tIdx];
        }
        short8 ah[2], al[2];
#pragma unroll
        for (int mt = 0; mt < 2; ++mt) {
            int off = (wm * 32 + mt * 16 + l15) * 136 + kf;
            ah[mt] = *(const short8*)&sAh[off];
            al[mt] = *(const short8*)&sAl[off];
        }
#pragma unroll
        for (int mt = 0; mt < 2; ++mt)
#pragma unroll
            for (int nt = 0; nt < 4; ++nt) {
                acc[mt][nt] = __builtin_amdgcn_mfma_f32_16x16x32_bf16(ah[mt], bh[nt], acc[mt][nt], 0, 0, 0);
                acc[mt][nt] = __builtin_amdgcn_mfma_f32_16x16x32_bf16(ah[mt], bl[nt], acc[mt][nt], 0, 0, 0);
                acc[mt][nt] = __builtin_amdgcn_mfma_f32_16x16x32_bf16(al[mt], bh[nt], acc[mt][nt], 0, 0, 0);
            }
    }

#pragma unroll
    for (int nt = 0; nt < 4; ++nt) {
        int c = wn * 64 + nt * 16 + l15;
        float b = bias[c];
        float s = 0.f, s2 = 0.f;
#pragma unroll
        for (int mt = 0; mt < 2; ++mt) {
#pragma unroll
            for (int r = 0; r < 4; ++r) {
                int gm = row0 + wm * 32 + mt * 16 + quad * 4 + r;
                float v = acc[mt][nt][r] + b;
                if (ELU_OUT) v = elu_f(v);
                if (gm < N) {
                    outp[(size_t)gm * D + c] = v;
                    if (ELU_OUT) outh16[(size_t)gm * D + c] = (_Float16)v;
                    if (STATS) { s += v; s2 += v * v; }
                }
            }
        }
        if (STATS) {
            atomicAdd(&bnsum[c], s);
            atomicAdd(&bnsum[D + c], s2);
        }
    }
    if (STATS) {
        __syncthreads();
        float* rep = colsum_out + (size_t)(blockIdx.x & (NREP - 1)) * 2 * D;
        if (tid < D) {
            atomicAdd(&rep[tid], bnsum[tid]);
            atomicAdd(&rep[D + tid], bnsum[D + tid]);
        }
    }
}

// ---------------- global mean pool ----------------
__global__ __launch_bounds__(128) void pool_kernel(
    const float* __restrict__ h, const int* __restrict__ batch,
    float* __restrict__ pooled, float* __restrict__ cnt, int N) {
    int c = threadIdx.x;
    int r0 = blockIdx.x * 256;
    if (r0 >= N) return;
    int rend = r0 + 256; if (rend > N) rend = N;
    int cur = batch[r0];
    float acc = 0.f;
    float cacc = 0.f;
    for (int r = r0; r < rend; ++r) {
        int b = batch[r];
        if (b != cur) {
            atomicAdd(&pooled[(size_t)cur * D + c], acc);
            if (c == 0) atomicAdd(&cnt[cur], cacc);
            acc = 0.f; cacc = 0.f; cur = b;
        }
        acc += h[(size_t)r * D + c];
        cacc += 1.f;
    }
    atomicAdd(&pooled[(size_t)cur * D + c], acc);
    if (c == 0) atomicAdd(&cnt[cur], cacc);
}

__global__ void final_linear_kernel(const float* __restrict__ pooled,
                                    const float* __restrict__ cnt,
                                    const float* __restrict__ linW,
                                    const float* __restrict__ linb,
                                    float* __restrict__ out, int G) {
    int t = blockIdx.x * blockDim.x + threadIdx.x;
    if (t >= G * 2) return;
    int g = t >> 1, o = t & 1;
    float inv = 1.0f / fmaxf(cnt[g], 1.0f);
    float s = linb[o];
    for (int c = 0; c < D; ++c)
        s += pooled[(size_t)g * D + c] * inv * linW[c * 2 + o];
    out[t] = s;
}

extern "C" void kernel_launch(void* const* d_in, const int* in_sizes, int n_in,
                              void* d_out, int out_size, void* d_ws, size_t ws_size,
                              hipStream_t stream) {
    const float* x      = (const float*)d_in[0];
    const int*  eidx    = (const int*)d_in[1];
    const int*  batch   = (const int*)d_in[2];
    const float* W1     = (const float*)d_in[3];
    const float* b1     = (const float*)d_in[4];
    const float* gamma  = (const float*)d_in[5];
    const float* beta   = (const float*)d_in[6];
    const float* W2     = (const float*)d_in[7];
    const float* b2     = (const float*)d_in[8];
    const float* linW   = (const float*)d_in[9];
    const float* linb   = (const float*)d_in[10];
    float* out = (float*)d_out;

    const int N = in_sizes[0] / D;
    const int E = in_sizes[1] / 2;
    const int L = in_sizes[3] / (D * D);
    const int G = out_size / 2;
    const int* esrc = eidx;
    const int* edst = eidx + E;
    const int NB = (N + 255) >> 8;

    size_t off = 0;
    auto carve = [&](size_t bytes) -> void* {
        void* p = (char*)d_ws + off;
        off += (bytes + 255) & ~(size_t)255;
        return p;
    };
    const size_t ND = (size_t)N * D;
    const int WTOT = 2 * L * D * D;
    float* z1     = (float*)carve(ND * 4);           // also aliased as CSR staging
    float* hbuf   = (float*)carve(ND * 4);
    _Float16* hhalf = (_Float16*)carve(ND * 2);
    unsigned short* Wph = (unsigned short*)carve((size_t)WTOT * 2);
    unsigned short* Wpl = (unsigned short*)carve((size_t)WTOT * 2);
    int* rowstart = (int*)carve((size_t)N * 4);
    int* rowend   = (int*)carve((size_t)N * 4);
    int* col      = (int*)carve((size_t)NB * BKT_CAP * 4);
    float* colsum4 = (float*)carve((size_t)4 * NREP * 2 * D * 4);
    int* gcursor  = (int*)carve(512 * 4);
    float* pooled = (float*)carve((size_t)G * D * 4); // contiguous with cnt: one memset
    float* cnt    = (float*)carve((size_t)G * 4);
    int2* staging = (int2*)z1;
    (void)ws_size; (void)n_in;

    hipMemsetAsync(colsum4, 0, (size_t)4 * NREP * 2 * D * 4, stream);
    hipMemsetAsync(pooled, 0, (size_t)G * D * 4 + (size_t)G * 4, stream);

    const int EB = (E + EDGES_PER_BLOCK - 1) / EDGES_PER_BLOCK;
    init_cursor_kernel<<<(NB + 255) / 256, 256, 0, stream>>>(gcursor, NB);
    bucket_scatter_kernel<<<EB, 256, 0, stream>>>(esrc, edst, gcursor, staging, E, NB);
    bucket_build_kernel<<<NB, 256, 0, stream>>>(staging, gcursor, rowstart, rowend, col, N);
    wprep_kernel<<<(WTOT + 255) / 256, 256, 0, stream>>>(W1, W2, Wph, Wpl, WTOT);
    to_half_kernel<<<(int)((ND / 4 + 255) / 256), 256, 0, stream>>>(x, hhalf, (int)(ND / 4));

    const int gemm_grid = (N + 63) / 64;
    const float* hin = x;
    for (int l = 0; l < L; ++l) {
        float* colsum = colsum4 + (size_t)l * NREP * 2 * D;
        gemm_mfma<true, false, true><<<gemm_grid, 256, 0, stream>>>(
            hin, hhalf, rowstart, rowend, col, nullptr,
            Wph + (size_t)(l * 2) * D * D, Wpl + (size_t)(l * 2) * D * D,
            b1 + (size_t)l * D, nullptr, nullptr, nullptr, z1, nullptr, colsum, N);
        gemm_mfma<false, true, false><<<gemm_grid, 256, 0, stream>>>(
            nullptr, nullptr, nullptr, nullptr, nullptr, z1,
            Wph + (size_t)(l * 2 + 1) * D * D, Wpl + (size_t)(l * 2 + 1) * D * D,
            b2 + (size_t)l * D, colsum, gamma + (size_t)l * D, beta + (size_t)l * D,
            hbuf, hhalf, nullptr, N);
        hin = hbuf;
    }

    pool_kernel<<<(N + 255) / 256, 128, 0, stream>>>(hbuf, batch, pooled, cnt, N);
    final_linear_kernel<<<(G * 2 + 255) / 256, 256, 0, stream>>>(pooled, cnt, linW, linb, out, G);
}

// Round 11
// 725.640 us; speedup vs baseline: 1.6028x; 1.1890x over previous
//
#include <hip/hip_runtime.h>
#include <cstdint>

#define D 128
#define BKT_SHIFT 8
#define BKT_CAP 5120
#define EDGES_PER_BLOCK 4096
#define NREP 8

typedef __attribute__((ext_vector_type(8))) short short8;
typedef __attribute__((ext_vector_type(4))) float floatx4;
typedef __attribute__((ext_vector_type(4))) _Float16 half4;
typedef __attribute__((ext_vector_type(8))) _Float16 half8;

__device__ __forceinline__ float elu_f(float x) {
    return x > 0.0f ? x : __expf(x) - 1.0f;
}

__device__ __forceinline__ void split_bf16(float a, unsigned short& hi, unsigned short& lo) {
    unsigned u = __builtin_bit_cast(unsigned, a);
    unsigned hb = u & 0xffff0000u;
    float hf = __builtin_bit_cast(float, hb);
    float rl = a - hf;
    unsigned ul = __builtin_bit_cast(unsigned, rl);
    hi = (unsigned short)(u >> 16);
    lo = (unsigned short)(ul >> 16);
}

// ================= bucketed CSR build (bump-allocated, no prepass) =================
__global__ void init_cursor_kernel(int* __restrict__ gcursor, int NB) {
    int t = blockIdx.x * 256 + threadIdx.x;
    if (t < NB) gcursor[t] = t * BKT_CAP;
}

__global__ __launch_bounds__(256) void bucket_scatter_kernel(
    const int* __restrict__ src, const int* __restrict__ dst,
    int* __restrict__ gcursor, int2* __restrict__ staging, int E, int NB) {
    __shared__ int lcnt[512];
    __shared__ int lbase[512];
    int t = threadIdx.x;
    lcnt[t] = 0; lcnt[t + 256] = 0;
    __syncthreads();
    int base = blockIdx.x * EDGES_PER_BLOCK;
    int s_[16], d_[16], r_[16];
#pragma unroll
    for (int i = 0; i < 16; ++i) {
        int idx = base + i * 256 + t;
        if (idx < E) {
            s_[i] = src[idx];
            d_[i] = dst[idx];
            r_[i] = atomicAdd(&lcnt[d_[i] >> BKT_SHIFT], 1);
        }
    }
    __syncthreads();
    for (int b = t; b < NB; b += 256) {
        int c = lcnt[b];
        if (c) lbase[b] = atomicAdd(&gcursor[b], c);
    }
    __syncthreads();
#pragma unroll
    for (int i = 0; i < 16; ++i) {
        int idx = base + i * 256 + t;
        if (idx < E) {
            int bkt = d_[i] >> BKT_SHIFT;
            staging[lbase[bkt] + r_[i]] = make_int2(s_[i], d_[i]);
        }
    }
}

__global__ __launch_bounds__(256) void bucket_build_kernel(
    const int2* __restrict__ staging, const int* __restrict__ gcursor,
    int* __restrict__ rowstart, int* __restrict__ rowend,
    int* __restrict__ col, int N) {
    __shared__ int hcnt[256];
    __shared__ int hoff[256];
    int t = threadIdx.x;
    int node0 = blockIdx.x << BKT_SHIFT;
    int off0 = blockIdx.x * BKT_CAP;
    int off1 = gcursor[blockIdx.x];
    hcnt[t] = 0;
    __syncthreads();
    for (int i = off0 + t; i < off1; i += 256)
        atomicAdd(&hcnt[staging[i].y - node0], 1);
    __syncthreads();
    int deg = hcnt[t];
    hoff[t] = deg;
    __syncthreads();
    for (int off = 1; off < 256; off <<= 1) {
        int u = (t >= off) ? hoff[t - off] : 0;
        __syncthreads();
        hoff[t] += u;
        __syncthreads();
    }
    int myoff = (t == 0) ? 0 : hoff[t - 1];
    __syncthreads();
    hoff[t] = myoff;
    hcnt[t] = 0;
    if (node0 + t < N) {
        rowstart[node0 + t] = off0 + myoff;
        rowend[node0 + t] = off0 + myoff + deg;
    }
    __syncthreads();
    for (int i = off0 + t; i < off1; i += 256) {
        int2 p = staging[i];
        int dl = p.y - node0;
        int pos = off0 + hoff[dl] + atomicAdd(&hcnt[dl], 1);
        col[pos] = p.x;
    }
}

// ---------------- fp32 -> fp16 convert (x before layer 0) ----------------
__global__ void to_half_kernel(const float* __restrict__ in, _Float16* __restrict__ outp, int n4) {
    int i = blockIdx.x * 256 + threadIdx.x;
    if (i >= n4) return;
    float4 v = ((const float4*)in)[i];
    half4 h = {(_Float16)v.x, (_Float16)v.y, (_Float16)v.z, (_Float16)v.w};
    ((half4*)outp)[i] = h;
}

// ---------------- W prep: fragment-permuted bf16 hi/lo layout ----------------
__global__ void wprep_kernel(const float* __restrict__ W1, const float* __restrict__ W2,
                             unsigned short* __restrict__ Wph, unsigned short* __restrict__ Wpl,
                             int total) {
    int idx = blockIdx.x * 256 + threadIdx.x;
    if (idx >= total) return;
    int mat = idx >> 14;
    int rem = idx & 16383;
    int tile = rem >> 9;
    int lane = (rem >> 3) & 63;
    int j = rem & 7;
    int ks = tile >> 3, nt = tile & 7;
    int n = nt * 16 + (lane & 15);
    int k = ks * 32 + (lane >> 4) * 8 + j;
    int l = mat >> 1;
    const float* W = (mat & 1) ? W2 : W1;
    float v = W[(size_t)l * D * D + k * D + n];
    unsigned short h, lo;
    split_bf16(v, h, lo);
    Wph[idx] = h;
    Wpl[idx] = lo;
}

// ---------------- MFMA GEMM (split-bf16, 3 terms), 64x128 tile ----------------
// GATHER: A = h16[node] + sum_neighbors h16[j] (16B half8 loads, fp32 accumulate).
// else:   A = elu(Z16*scale+shift), scale/shift from 8-replica colsum_in (BN fused).
// Output written fp16 only. STATS: fp32 col sum/sumsq -> replicated colsum_out.
template <bool GATHER, bool ELU_OUT, bool STATS>
__global__ __launch_bounds__(256, 4) void gemm_mfma(
    const _Float16* __restrict__ Hh,
    const int* __restrict__ rowstart, const int* __restrict__ rowend,
    const int* __restrict__ col,
    const _Float16* __restrict__ Z,
    const unsigned short* __restrict__ Wph, const unsigned short* __restrict__ Wpl,
    const float* __restrict__ bias,
    const float* __restrict__ colsum_in, const float* __restrict__ gamma,
    const float* __restrict__ beta,
    _Float16* __restrict__ outp16, float* __restrict__ colsum_out, int N) {
    __shared__ unsigned short sAh[64 * 136];
    __shared__ unsigned short sAl[64 * 136];
    __shared__ float bnsum[2 * D];
    __shared__ float s_sc[D];
    __shared__ float s_sh[D];
    const int tid = threadIdx.x;
    const int row0 = blockIdx.x * 64;

    if (STATS && tid < 2 * D) bnsum[tid] = 0.f;

    if (GATHER) {
        const int rg = tid >> 4;     // 0..15 row groups (4 rows each)
        const int q = tid & 15;      // half8 lane (8 channels)
        const half8* hh8 = (const half8*)Hh;
#pragma unroll
        for (int i = 0; i < 4; ++i) {
            int r = rg * 4 + i;
            int node = row0 + r;
            float a0 = 0.f, a1 = 0.f, a2 = 0.f, a3 = 0.f;
            float a4 = 0.f, a5 = 0.f, a6 = 0.f, a7 = 0.f;
            if (node < N) {
                half8 sf = hh8[(size_t)node * 16 + q];
                a0 = (float)sf[0]; a1 = (float)sf[1]; a2 = (float)sf[2]; a3 = (float)sf[3];
                a4 = (float)sf[4]; a5 = (float)sf[5]; a6 = (float)sf[6]; a7 = (float)sf[7];
                int e0 = rowstart[node], e1 = rowend[node];
                int e = e0;
                for (; e + 7 < e1; e += 8) {
                    int j0 = col[e],     j1 = col[e + 1], j2 = col[e + 2], j3 = col[e + 3];
                    int j4 = col[e + 4], j5 = col[e + 5], j6 = col[e + 6], j7 = col[e + 7];
                    half8 v0 = hh8[(size_t)j0 * 16 + q];
                    half8 v1 = hh8[(size_t)j1 * 16 + q];
                    half8 v2 = hh8[(size_t)j2 * 16 + q];
                    half8 v3 = hh8[(size_t)j3 * 16 + q];
                    half8 v4 = hh8[(size_t)j4 * 16 + q];
                    half8 v5 = hh8[(size_t)j5 * 16 + q];
                    half8 v6 = hh8[(size_t)j6 * 16 + q];
                    half8 v7 = hh8[(size_t)j7 * 16 + q];
#pragma unroll
                    for (int j = 0; j < 1; ++j) {  // keep scope tidy
                        a0 += ((float)v0[0] + (float)v1[0] + (float)v2[0] + (float)v3[0])
                            + ((float)v4[0] + (float)v5[0] + (float)v6[0] + (float)v7[0]);
                        a1 += ((float)v0[1] + (float)v1[1] + (float)v2[1] + (float)v3[1])
                            + ((float)v4[1] + (float)v5[1] + (float)v6[1] + (float)v7[1]);
                        a2 += ((float)v0[2] + (float)v1[2] + (float)v2[2] + (float)v3[2])
                            + ((float)v4[2] + (float)v5[2] + (float)v6[2] + (float)v7[2]);
                        a3 += ((float)v0[3] + (float)v1[3] + (float)v2[3] + (float)v3[3])
                            + ((float)v4[3] + (float)v5[3] + (float)v6[3] + (float)v7[3]);
                        a4 += ((float)v0[4] + (float)v1[4] + (float)v2[4] + (float)v3[4])
                            + ((float)v4[4] + (float)v5[4] + (float)v6[4] + (float)v7[4]);
                        a5 += ((float)v0[5] + (float)v1[5] + (float)v2[5] + (float)v3[5])
                            + ((float)v4[5] + (float)v5[5] + (float)v6[5] + (float)v7[5]);
                        a6 += ((float)v0[6] + (float)v1[6] + (float)v2[6] + (float)v3[6])
                            + ((float)v4[6] + (float)v5[6] + (float)v6[6] + (float)v7[6]);
                        a7 += ((float)v0[7] + (float)v1[7] + (float)v2[7] + (float)v3[7])
                            + ((float)v4[7] + (float)v5[7] + (float)v6[7] + (float)v7[7]);
                    }
                }
                for (; e < e1; ++e) {
                    half8 v = hh8[(size_t)col[e] * 16 + q];
                    a0 += (float)v[0]; a1 += (float)v[1]; a2 += (float)v[2]; a3 += (float)v[3];
                    a4 += (float)v[4]; a5 += (float)v[5]; a6 += (float)v[6]; a7 += (float)v[7];
                }
            }
            ushort4 h0, l0, h1, l1;
            split_bf16(a0, h0.x, l0.x); split_bf16(a1, h0.y, l0.y);
            split_bf16(a2, h0.z, l0.z); split_bf16(a3, h0.w, l0.w);
            split_bf16(a4, h1.x, l1.x); split_bf16(a5, h1.y, l1.y);
            split_bf16(a6, h1.z, l1.z); split_bf16(a7, h1.w, l1.w);
            *(ushort4*)&sAh[r * 136 + q * 8] = h0;
            *(ushort4*)&sAh[r * 136 + q * 8 + 4] = h1;
            *(ushort4*)&sAl[r * 136 + q * 8] = l0;
            *(ushort4*)&sAl[r * 136 + q * 8 + 4] = l1;
        }
    } else {
        if (tid < D) {
            float s = 0.f, s2 = 0.f;
#pragma unroll
            for (int rp = 0; rp < NREP; ++rp) {
                s  += colsum_in[rp * 2 * D + tid];
                s2 += colsum_in[rp * 2 * D + D + tid];
            }
            float invN = 1.0f / (float)N;
            float mu = s * invN;
            float var = s2 * invN - mu * mu;
            float rs = rsqrtf(var + 1e-5f);
            float sc = gamma[tid] * rs;
            s_sc[tid] = sc;
            s_sh[tid] = beta[tid] - mu * sc;
        }
        __syncthreads();
#pragma unroll
        for (int it = 0; it < 4; ++it) {
            int idx = tid + it * 256;
            int r = idx >> 4;           // 0..63
            int q8 = (idx & 15) * 8;    // channel offset
            int gr = row0 + r;
            half8 z = {};
            if (gr < N) z = *(const half8*)&Z[(size_t)gr * D + q8];
            ushort4 h0, l0, h1, l1;
            float v0 = elu_f((float)z[0] * s_sc[q8 + 0] + s_sh[q8 + 0]);
            float v1 = elu_f((float)z[1] * s_sc[q8 + 1] + s_sh[q8 + 1]);
            float v2 = elu_f((float)z[2] * s_sc[q8 + 2] + s_sh[q8 + 2]);
            float v3 = elu_f((float)z[3] * s_sc[q8 + 3] + s_sh[q8 + 3]);
            float v4 = elu_f((float)z[4] * s_sc[q8 + 4] + s_sh[q8 + 4]);
            float v5 = elu_f((float)z[5] * s_sc[q8 + 5] + s_sh[q8 + 5]);
            float v6 = elu_f((float)z[6] * s_sc[q8 + 6] + s_sh[q8 + 6]);
            float v7 = elu_f((float)z[7] * s_sc[q8 + 7] + s_sh[q8 + 7]);
            split_bf16(v0, h0.x, l0.x); split_bf16(v1, h0.y, l0.y);
            split_bf16(v2, h0.z, l0.z); split_bf16(v3, h0.w, l0.w);
            split_bf16(v4, h1.x, l1.x); split_bf16(v5, h1.y, l1.y);
            split_bf16(v6, h1.z, l1.z); split_bf16(v7, h1.w, l1.w);
            *(ushort4*)&sAh[r * 136 + q8] = h0;
            *(ushort4*)&sAh[r * 136 + q8 + 4] = h1;
            *(ushort4*)&sAl[r * 136 + q8] = l0;
            *(ushort4*)&sAl[r * 136 + q8 + 4] = l1;
        }
    }
    __syncthreads();

    const int wave = tid >> 6, lane = tid & 63;
    const int wm = wave >> 1, wn = wave & 1;
    const int l15 = lane & 15, quad = lane >> 4;
    const short8* bph = (const short8*)Wph;
    const short8* bpl = (const short8*)Wpl;

    floatx4 acc[2][4];
#pragma unroll
    for (int mt = 0; mt < 2; ++mt)
#pragma unroll
        for (int nt = 0; nt < 4; ++nt)
            acc[mt][nt] = (floatx4){0.f, 0.f, 0.f, 0.f};

#pragma unroll
    for (int ks = 0; ks < 4; ++ks) {
        const int kf = ks * 32 + quad * 8;
        short8 bh[4], bl[4];
#pragma unroll
        for (int nt = 0; nt < 4; ++nt) {
            int tIdx = (ks * 8 + wn * 4 + nt) * 64 + lane;
            bh[nt] = bph[tIdx];
            bl[nt] = bpl[tIdx];
        }
        short8 ah[2], al[2];
#pragma unroll
        for (int mt = 0; mt < 2; ++mt) {
            int off = (wm * 32 + mt * 16 + l15) * 136 + kf;
            ah[mt] = *(const short8*)&sAh[off];
            al[mt] = *(const short8*)&sAl[off];
        }
#pragma unroll
        for (int mt = 0; mt < 2; ++mt)
#pragma unroll
            for (int nt = 0; nt < 4; ++nt) {
                acc[mt][nt] = __builtin_amdgcn_mfma_f32_16x16x32_bf16(ah[mt], bh[nt], acc[mt][nt], 0, 0, 0);
                acc[mt][nt] = __builtin_amdgcn_mfma_f32_16x16x32_bf16(ah[mt], bl[nt], acc[mt][nt], 0, 0, 0);
                acc[mt][nt] = __builtin_amdgcn_mfma_f32_16x16x32_bf16(al[mt], bh[nt], acc[mt][nt], 0, 0, 0);
            }
    }

#pragma unroll
    for (int nt = 0; nt < 4; ++nt) {
        int c = wn * 64 + nt * 16 + l15;
        float b = bias[c];
        float s = 0.f, s2 = 0.f;
#pragma unroll
        for (int mt = 0; mt < 2; ++mt) {
#pragma unroll
            for (int r = 0; r < 4; ++r) {
                int gm = row0 + wm * 32 + mt * 16 + quad * 4 + r;
                float v = acc[mt][nt][r] + b;
                if (ELU_OUT) v = elu_f(v);
                if (gm < N) {
                    outp16[(size_t)gm * D + c] = (_Float16)v;
                    if (STATS) { s += v; s2 += v * v; }
                }
            }
        }
        if (STATS) {
            atomicAdd(&bnsum[c], s);
            atomicAdd(&bnsum[D + c], s2);
        }
    }
    if (STATS) {
        __syncthreads();
        float* rep = colsum_out + (size_t)(blockIdx.x & (NREP - 1)) * 2 * D;
        if (tid < D) {
            atomicAdd(&rep[tid], bnsum[tid]);
            atomicAdd(&rep[D + tid], bnsum[D + tid]);
        }
    }
}

// ---------------- global mean pool (fp16 input) ----------------
__global__ __launch_bounds__(128) void pool_kernel(
    const _Float16* __restrict__ h, const int* __restrict__ batch,
    float* __restrict__ pooled, float* __restrict__ cnt, int N) {
    int c = threadIdx.x;
    int r0 = blockIdx.x * 256;
    if (r0 >= N) return;
    int rend = r0 + 256; if (rend > N) rend = N;
    int cur = batch[r0];
    float acc = 0.f;
    float cacc = 0.f;
    for (int r = r0; r < rend; ++r) {
        int b = batch[r];
        if (b != cur) {
            atomicAdd(&pooled[(size_t)cur * D + c], acc);
            if (c == 0) atomicAdd(&cnt[cur], cacc);
            acc = 0.f; cacc = 0.f; cur = b;
        }
        acc += (float)h[(size_t)r * D + c];
        cacc += 1.f;
    }
    atomicAdd(&pooled[(size_t)cur * D + c], acc);
    if (c == 0) atomicAdd(&cnt[cur], cacc);
}

__global__ void final_linear_kernel(const float* __restrict__ pooled,
                                    const float* __restrict__ cnt,
                                    const float* __restrict__ linW,
                                    const float* __restrict__ linb,
                                    float* __restrict__ out, int G) {
    int t = blockIdx.x * blockDim.x + threadIdx.x;
    if (t >= G * 2) return;
    int g = t >> 1, o = t & 1;
    float inv = 1.0f / fmaxf(cnt[g], 1.0f);
    float s = linb[o];
    for (int c = 0; c < D; ++c)
        s += pooled[(size_t)g * D + c] * inv * linW[c * 2 + o];
    out[t] = s;
}

extern "C" void kernel_launch(void* const* d_in, const int* in_sizes, int n_in,
                              void* d_out, int out_size, void* d_ws, size_t ws_size,
                              hipStream_t stream) {
    const float* x      = (const float*)d_in[0];
    const int*  eidx    = (const int*)d_in[1];
    const int*  batch   = (const int*)d_in[2];
    const float* W1     = (const float*)d_in[3];
    const float* b1     = (const float*)d_in[4];
    const float* gamma  = (const float*)d_in[5];
    const float* beta   = (const float*)d_in[6];
    const float* W2     = (const float*)d_in[7];
    const float* b2     = (const float*)d_in[8];
    const float* linW   = (const float*)d_in[9];
    const float* linb   = (const float*)d_in[10];
    float* out = (float*)d_out;

    const int N = in_sizes[0] / D;
    const int E = in_sizes[1] / 2;
    const int L = in_sizes[3] / (D * D);
    const int G = out_size / 2;
    const int* esrc = eidx;
    const int* edst = eidx + E;
    const int NB = (N + 255) >> 8;

    size_t off = 0;
    auto carve = [&](size_t bytes) -> void* {
        void* p = (char*)d_ws + off;
        off += (bytes + 255) & ~(size_t)255;
        return p;
    };
    const size_t ND = (size_t)N * D;
    const int WTOT = 2 * L * D * D;
    _Float16* z16   = (_Float16*)carve(ND * 2);      // also aliased as CSR staging (16MB <= 25.6MB)
    _Float16* hhalf = (_Float16*)carve(ND * 2);
    unsigned short* Wph = (unsigned short*)carve((size_t)WTOT * 2);
    unsigned short* Wpl = (unsigned short*)carve((size_t)WTOT * 2);
    int* rowstart = (int*)carve((size_t)N * 4);
    int* rowend   = (int*)carve((size_t)N * 4);
    int* col      = (int*)carve((size_t)NB * BKT_CAP * 4);
    float* colsum4 = (float*)carve((size_t)4 * NREP * 2 * D * 4);
    int* gcursor  = (int*)carve(512 * 4);
    float* pooled = (float*)carve((size_t)G * D * 4); // contiguous with cnt: one memset
    float* cnt    = (float*)carve((size_t)G * 4);
    int2* staging = (int2*)z16;
    (void)ws_size; (void)n_in;

    hipMemsetAsync(colsum4, 0, (size_t)4 * NREP * 2 * D * 4, stream);
    hipMemsetAsync(pooled, 0, (size_t)G * D * 4 + (size_t)G * 4, stream);

    const int EB = (E + EDGES_PER_BLOCK - 1) / EDGES_PER_BLOCK;
    init_cursor_kernel<<<(NB + 255) / 256, 256, 0, stream>>>(gcursor, NB);
    bucket_scatter_kernel<<<EB, 256, 0, stream>>>(esrc, edst, gcursor, staging, E, NB);
    bucket_build_kernel<<<NB, 256, 0, stream>>>(staging, gcursor, rowstart, rowend, col, N);
    wprep_kernel<<<(WTOT + 255) / 256, 256, 0, stream>>>(W1, W2, Wph, Wpl, WTOT);
    to_half_kernel<<<(int)((ND / 4 + 255) / 256), 256, 0, stream>>>(x, hhalf, (int)(ND / 4));

    const int gemm_grid = (N + 63) / 64;
    for (int l = 0; l < L; ++l) {
        float* colsum = colsum4 + (size_t)l * NREP * 2 * D;
        gemm_mfma<true, false, true><<<gemm_grid, 256, 0, stream>>>(
            hhalf, rowstart, rowend, col, nullptr,
            Wph + (size_t)(l * 2) * D * D, Wpl + (size_t)(l * 2) * D * D,
            b1 + (size_t)l * D, nullptr, nullptr, nullptr, z16, colsum, N);
        gemm_mfma<false, true, false><<<gemm_grid, 256, 0, stream>>>(
            nullptr, nullptr, nullptr, nullptr, z16,
            Wph + (size_t)(l * 2 + 1) * D * D, Wpl + (size_t)(l * 2 + 1) * D * D,
            b2 + (size_t)l * D, colsum, gamma + (size_t)l * D, beta + (size_t)l * D,
            hhalf, nullptr, N);
    }

    pool_kernel<<<(N + 255) / 256, 128, 0, stream>>>(hhalf, batch, pooled, cnt, N);
    final_linear_kernel<<<(G * 2 + 255) / 256, 256, 0, stream>>>(pooled, cnt, linW, linb, out, G);
}